// Round 3
// baseline (785.829 us; speedup 1.0000x reference)
//
#include <hip/hip_runtime.h>

typedef unsigned short u16;
typedef unsigned int u32;
typedef unsigned long long u64;

#define B_TOTAL 65536
#define H 512
#define D 64
#define BM 64

typedef __bf16 bf16x8 __attribute__((ext_vector_type(8)));
typedef float f32x4 __attribute__((ext_vector_type(4)));

__device__ __forceinline__ u32 f2b(float f) {  // fp32 -> bf16 bits, RNE
  u32 u = __builtin_bit_cast(u32, f);
  return (u + 0x7fffu + ((u >> 16) & 1u)) >> 16;
}
__device__ __forceinline__ float b2f(u32 bits) {
  return __builtin_bit_cast(float, bits << 16);
}

// ---- workspace layout (bf16 element offsets) ----
// Weight regions are FRAGMENT-PACKED: for logical B-matrix M[NN][KK],
// packed[( (n>>4)*(KK/32) + (k>>5) )*512 + lane*8 + j] = M[n][k],
// n = ntile*16 + (lane&15), k = kstep*32 + (lane>>4)*8 + j.
#define OFF_Wz0b 0          /* [N=512][K=64]  fwd L0 */
#define OFF_Wx0b 32768
#define OFF_Wx1b 65536
#define OFF_Wx2b 98304
#define OFF_Wz1b 131072     /* [N=512][K=512] fwd */
#define OFF_Wz2b 393216
#define OFF_Wz3b 655360
#define OFF_Wz1t 917504     /* [N=512][K=512] transposed, bwd */
#define OFF_Wz2t 1179648
#define OFF_Wz3t 1441792
#define OFF_Wz0t 1703936    /* [N=64][K=512] transposed grad weights */
#define OFF_Wx0t 1736704
#define OFF_Wx1t 1769472
#define OFF_Wx2t 1802240
#define OFF_WEND 1835008
#define SLAB_ELEMS (B_TOTAL * H)          /* 33,554,432 bf16 per slab */
#define OFF_S0 OFF_WEND
#define OFF_S1 (OFF_S0 + SLAB_ELEMS)
#define OFF_S2 (OFF_S1 + SLAB_ELEMS)
#define WS_ELEMS (OFF_S2 + SLAB_ELEMS)    /* ~102.5M elems = ~205 MB */

// ---- weight prep: fp32 -> bf16, fragment-packed (+ transposed variants) ----
__global__ __launch_bounds__(256) void prep_kernel(
    const float* __restrict__ Wz0, const float* __restrict__ Wz1,
    const float* __restrict__ Wz2, const float* __restrict__ Wz3,
    const float* __restrict__ Wx0, const float* __restrict__ Wx1,
    const float* __restrict__ Wx2, u16* __restrict__ wsb) {
  int i = blockIdx.x * 256 + threadIdx.x;   // grid exactly covers OFF_WEND
  const float* src;
  int NN, KK, trans, p;
  if (i < 131072) {                          // x-path fwd: [512][64] direct
    int r = i >> 15; p = i & 32767;
    src = (r == 0) ? Wz0 : (r == 1) ? Wx0 : (r == 2) ? Wx1 : Wx2;
    NN = 512; KK = 64; trans = 0;
  } else if (i < 917504) {                   // H fwd: [512][512] direct
    int j = i - 131072; int r = j >> 18; p = j & 262143;
    src = (r == 0) ? Wz1 : (r == 1) ? Wz2 : Wz3;
    NN = 512; KK = 512; trans = 0;
  } else if (i < 1703936) {                  // H bwd: transposed
    int j = i - 917504; int r = j >> 18; p = j & 262143;
    src = (r == 0) ? Wz1 : (r == 1) ? Wz2 : Wz3;
    NN = 512; KK = 512; trans = 1;
  } else {                                   // grad weights: [64][512] = W^T
    int j = i - 1703936; int r = j >> 15; p = j & 32767;
    src = (r == 0) ? Wz0 : (r == 1) ? Wx0 : (r == 2) ? Wx1 : Wx2;
    NN = 64; KK = 512; trans = 1;
  }
  int jj = p & 7, lane = (p >> 3) & 63, blk = p >> 9;
  int kt_sh = (KK == 64) ? 1 : 4;            // log2(KK/32)
  int ntile = blk >> kt_sh;
  int kstep = blk & ((1 << kt_sh) - 1);
  int n = ntile * 16 + (lane & 15);
  int k = kstep * 32 + ((lane >> 4) << 3) + jj;
  float v = trans ? src[k * NN + n] : src[n * KK + k];
  wsb[i] = (u16)f2b(v);
}

__global__ __launch_bounds__(256) void fill_sentinel(float* out, int n) {
  int i = blockIdx.x * 256 + threadIdx.x;
  if (i < n) out[i] = 12345.0f;   // unmistakable "workspace too small" marker
}

// ---- fully-fused ICNN fwd+bwd (single GEMM kernel) ----
// 512 thr = 8 waves, BM=64 rows. ROUND-3 GEOMETRY (post-spill-postmortem):
// wave w owns 32 ROWS x 64 cols per pass (acc[2][4] = 32 acc regs); each GEMM
// runs as two row-half passes (h=0: rows 0-31, h=1: rows 32-63). Worst-case
// live set ~90 regs << 128 cap -> no spills BY CONSTRUCTION (rounds 1-2 died
// on acc=64 + 64 arch not fitting: +1 GB scratch HBM traffic).
// Schedule per layer: [fwdH-h1] bar [epi-h1(VALU) || fwdH-h2(MFMA)] bar
// [epi-h2] bar — the middle phase mixes epilogue VALU with MFMA so the
// 4 waves/SIMD (2 blocks/CU x 8 waves) overlap the two pipes.
// LDS = zbuf 64K + union{xbuf 9K, park 16K} = 80 KB exactly -> 2 blocks/CU.
__global__ __launch_bounds__(512, 4) void icnn_kernel(
    const float* __restrict__ state,
    const float* __restrict__ bz0, const float* __restrict__ bx0,
    const float* __restrict__ bx1, const float* __restrict__ bx2,
    const float* __restrict__ WzL, const float* __restrict__ WxL,
    u16* __restrict__ wsw, float* __restrict__ out) {
  __shared__ u16 zbuf[BM * H];      // XOR-swizzled activations, 64 KB
  __shared__ f32x4 park[16 * 64];   // 16 KB: x-staging early, fp32 grad park late
  u16* xbuf = (u16*)park;           // x staging needs 64*72 u16 = 9216 B

  const int tid = threadIdx.x;
  const int w = tid >> 6;           // 0..7
  const int lane = tid & 63;
  const int l15 = lane & 15;
  const int q = lane >> 4;
  const int blk = blockIdx.x;

  const u16* Wz0b = wsw + OFF_Wz0b;
  const u16* Wx0b = wsw + OFF_Wx0b;
  const u16* Wx1b = wsw + OFF_Wx1b;
  const u16* Wx2b = wsw + OFF_Wx2b;
  const u16* Wz1b = wsw + OFF_Wz1b;
  const u16* Wz2b = wsw + OFF_Wz2b;
  const u16* Wz3b = wsw + OFF_Wz3b;
  const u16* Wz1t = wsw + OFF_Wz1t;
  const u16* Wz2t = wsw + OFF_Wz2t;
  const u16* Wz3t = wsw + OFF_Wz3t;
  const u16* Wz0t = wsw + OFF_Wz0t;
  const u16* Wx0t = wsw + OFF_Wx0t;
  const u16* Wx1t = wsw + OFF_Wx1t;
  const u16* Wx2t = wsw + OFF_Wx2t;
  u64* slab0 = (u64*)(wsw + OFF_S0);
  u64* slab1 = (u64*)(wsw + OFF_S1);
  u64* slab2 = (u64*)(wsw + OFF_S2);

  // ---- stage x = state-1 into xbuf (bf16, padded row-major) ----
  {
    int r = tid >> 3, c0 = (tid & 7) << 3;   // 64 rows x 8 chunks of 8 floats
    const float* p = state + (blk * BM + r) * D + c0;
    f32x4 v0 = __builtin_nontemporal_load((const f32x4*)p);
    f32x4 v1 = __builtin_nontemporal_load((const f32x4*)(p + 4));
    u32* dst = (u32*)&xbuf[r * 72 + c0];
    dst[0] = f2b(v0[0] - 1.0f) | (f2b(v0[1] - 1.0f) << 16);
    dst[1] = f2b(v0[2] - 1.0f) | (f2b(v0[3] - 1.0f) << 16);
    dst[2] = f2b(v1[0] - 1.0f) | (f2b(v1[1] - 1.0f) << 16);
    dst[3] = f2b(v1[2] - 1.0f) | (f2b(v1[3] - 1.0f) << 16);
  }

  f32x4 acc[2][4];                  // 32 acc regs: one row-half x 64 cols
  const f32x4 Z = {0.f, 0.f, 0.f, 0.f};

  auto ldA = [&](int rt, int step) -> bf16x8 {     // LDS A-frag (swizzled)
    int m = rt * 16 + l15;
    int idx = m * H + (((step * 4 + q) ^ (m & 7)) << 3);
    return *(const bf16x8*)(&zbuf[idx]);
  };
  auto ldX = [&](int rt, int ks) -> bf16x8 {       // x A-frag from padded xbuf
    return *(const bf16x8*)(&xbuf[(rt * 16 + l15) * 72 + ks * 32 + q * 8]);
  };
  auto wrZ = [&](int row, int n, u16 bits) {       // swizzled LDS bf16 write
    zbuf[row * H + ((((n >> 3) ^ (row & 7))) << 3) + (n & 7)] = bits;
  };
  auto zeroAcc = [&]() {
#pragma unroll
    for (int mt = 0; mt < 2; ++mt)
#pragma unroll
      for (int nt = 0; nt < 4; ++nt) acc[mt][nt] = Z;
  };

  // acc = x @ Wx^T (K=64), rows of half h. Zero-starts acc.
  auto fwdX = [&](const u16* Wxp, int h) {
    const u16* xb = Wxp + lane * 8;
#pragma unroll
    for (int ks = 0; ks < 2; ++ks) {
      bf16x8 ax[2];
#pragma unroll
      for (int mt = 0; mt < 2; ++mt) ax[mt] = ldX(h * 2 + mt, ks);
      bf16x8 b4[4];
#pragma unroll
      for (int nt = 0; nt < 4; ++nt)
        b4[nt] = *(const bf16x8*)(xb + ((w * 4 + nt) * 2 + ks) * 512);
#pragma unroll
      for (int nt = 0; nt < 4; ++nt)
#pragma unroll
        for (int mt = 0; mt < 2; ++mt)
          acc[mt][nt] = __builtin_amdgcn_mfma_f32_16x16x32_bf16(
              ax[mt], b4[nt], (ks == 0) ? Z : acc[mt][nt], 0, 0, 0);
    }
  };

  // acc += zbuf(rows of half h) @ W^T (K=512). Weights stream global->VGPR.
  auto fwdH = [&](const u16* Wp, int h) {
    const u16* wb = Wp + (w * 64) * 512 + lane * 8;  // wave's 64-col strip
#pragma unroll 2
    for (int st = 0; st < 16; ++st) {
      bf16x8 a[2];
#pragma unroll
      for (int mt = 0; mt < 2; ++mt) a[mt] = ldA(h * 2 + mt, st);
      bf16x8 b[4];
#pragma unroll
      for (int nt = 0; nt < 4; ++nt)
        b[nt] = *(const bf16x8*)(wb + (nt * 16 + st) * 512);
#pragma unroll
      for (int nt = 0; nt < 4; ++nt)
#pragma unroll
        for (int mt = 0; mt < 2; ++mt)
          acc[mt][nt] = __builtin_amdgcn_mfma_f32_16x16x32_bf16(a[mt], b[nt],
                                                                acc[mt][nt], 0, 0, 0);
    }
  };

  // forward epilogue (half h): a+=bias; z=softplus -> zbuf; s=sigmoid -> slab
  auto fwd_epi = [&](const float* biasp, u64* slab, int h) {
#pragma unroll
    for (int mt = 0; mt < 2; ++mt) {
      int rt = h * 2 + mt;
#pragma unroll
      for (int nt = 0; nt < 4; ++nt) {
        int n = (w * 4 + nt) * 16 + l15;
        float bias = biasp[n];
        f32x4 A = acc[mt][nt];
        u64 pack = 0;
#pragma unroll
        for (int r = 0; r < 4; ++r) {
          float a = A[r] + bias;
          float t = __expf(-a);
          float u = 1.0f + t;
          float s = __builtin_amdgcn_rcpf(u);     // sigmoid(a)
          float z = a + __logf(u);                // softplus(a)
          pack |= (u64)f2b(s) << (16 * r);
          wrZ(rt * 16 + q * 4 + r, n, (u16)f2b(z));
        }
        slab[((blk * 8 + w) * 16 + rt * 4 + nt) * 64 + lane] = pack;
      }
    }
  };
  auto d3_epi = [&](const float* biasp, int h) {  // d3 = WzL * sigmoid(a3)
#pragma unroll
    for (int mt = 0; mt < 2; ++mt) {
      int rt = h * 2 + mt;
#pragma unroll
      for (int nt = 0; nt < 4; ++nt) {
        int n = (w * 4 + nt) * 16 + l15;
        float bias = biasp[n];
        float wl = WzL[n];
        f32x4 A = acc[mt][nt];
#pragma unroll
        for (int r = 0; r < 4; ++r) {
          float a = A[r] + bias;
          float t = __expf(-a);
          float s = __builtin_amdgcn_rcpf(1.0f + t);
          wrZ(rt * 16 + q * 4 + r, n, (u16)f2b(wl * s));
        }
      }
    }
  };
  // d = g * s -> zbuf (half h)
  auto bwd_epi = [&](const u64* slab, int h) {
#pragma unroll
    for (int mt = 0; mt < 2; ++mt) {
      int rt = h * 2 + mt;
      u64 v[4];
#pragma unroll
      for (int nt = 0; nt < 4; ++nt)
        v[nt] = slab[((blk * 8 + w) * 16 + rt * 4 + nt) * 64 + lane];
#pragma unroll
      for (int nt = 0; nt < 4; ++nt) {
        int n = (w * 4 + nt) * 16 + l15;
        f32x4 A = acc[mt][nt];
#pragma unroll
        for (int r = 0; r < 4; ++r) {
          float s = b2f((u32)(v[nt] >> (16 * r)) & 0xffffu);
          wrZ(rt * 16 + q * 4 + r, n, (u16)f2b(A[r] * s));
        }
      }
    }
  };

  // grad mini-phase: park += zbuf(d) @ Wg (main acc is DEAD here).
  // Wave w owns tiles t0=w, t1=w+8: rt = w&3, cols c0=w>>2, c0+2.
  auto minigrad = [&](const u16* Wg, bool init) {
    int rt = w & 3, c0 = w >> 2;
    const u16* gb = Wg + lane * 8;
    f32x4 t0 = Z, t1 = Z;
#pragma unroll 2
    for (int st = 0; st < 16; ++st) {
      bf16x8 a = ldA(rt, st);
      bf16x8 g0 = *(const bf16x8*)(gb + (c0 * 16 + st) * 512);
      bf16x8 g1 = *(const bf16x8*)(gb + ((c0 + 2) * 16 + st) * 512);
      t0 = __builtin_amdgcn_mfma_f32_16x16x32_bf16(a, g0, t0, 0, 0, 0);
      t1 = __builtin_amdgcn_mfma_f32_16x16x32_bf16(a, g1, t1, 0, 0, 0);
    }
    if (init) {
      park[w * 64 + lane] = t0;
      park[(w + 8) * 64 + lane] = t1;
    } else {
      park[w * 64 + lane] += t0;
      park[(w + 8) * 64 + lane] += t1;
    }
  };

  // ---------------- forward ----------------
  __syncthreads();                          // xbuf ready
  // L0: a0 = x@Wz0 (K=64). zbuf has no readers yet -> no inner barriers.
  fwdX(Wz0b, 0); fwd_epi(bz0, slab0, 0);
  fwdX(Wz0b, 1); fwd_epi(bz0, slab0, 1);
  __syncthreads();                          // z0 complete
  // L1: a1 = z0@Wz1 + x@Wx0
  fwdX(Wx0b, 0); fwdH(Wz1b, 0);
  __syncthreads();                          // reads of z0 rows 0-31 done
  fwd_epi(bx0, slab1, 0);                   // write z1 rows 0-31 (VALU)
  fwdX(Wx0b, 1); fwdH(Wz1b, 1);            // read z0 rows 32-63 (MFMA)
  __syncthreads();
  fwd_epi(bx0, slab1, 1);                   // z1 rows 32-63
  __syncthreads();
  // L2
  fwdX(Wx1b, 0); fwdH(Wz2b, 0);
  __syncthreads();
  fwd_epi(bx1, slab2, 0);
  fwdX(Wx1b, 1); fwdH(Wz2b, 1);
  __syncthreads();
  fwd_epi(bx1, slab2, 1);
  __syncthreads();
  // L3: a3 (last use of xbuf)
  fwdX(Wx2b, 0); fwdH(Wz3b, 0);
  __syncthreads();
  d3_epi(bx2, 0);                           // d3 rows 0-31
  fwdX(Wx2b, 1); fwdH(Wz3b, 1);
  __syncthreads();
  d3_epi(bx2, 1);                           // d3 rows 32-63
  __syncthreads();
  // ---------------- backward ----------------
  // l=3: d2 = (d3@Wz3t) * s2 ; park = d3@Wx2t
  minigrad(Wx2t, true);                     // xbuf dead -> park init OK
  zeroAcc(); fwdH(Wz3t, 0);
  __syncthreads();
  bwd_epi(slab2, 0);                        // d2 rows 0-31
  zeroAcc(); fwdH(Wz3t, 1);
  __syncthreads();
  bwd_epi(slab2, 1);
  __syncthreads();
  // l=2
  minigrad(Wx1t, false);
  zeroAcc(); fwdH(Wz2t, 0);
  __syncthreads();
  bwd_epi(slab1, 0);
  zeroAcc(); fwdH(Wz2t, 1);
  __syncthreads();
  bwd_epi(slab1, 1);
  __syncthreads();
  // l=1
  minigrad(Wx0t, false);
  zeroAcc(); fwdH(Wz1t, 0);
  __syncthreads();
  bwd_epi(slab0, 0);
  zeroAcc(); fwdH(Wz1t, 1);
  __syncthreads();
  bwd_epi(slab0, 1);
  __syncthreads();
  // ---- final: out = d0@Wz0t + park + WxL ----
  {
    int rt = w & 3, c0 = w >> 2;
    const u16* gb = Wz0t + lane * 8;
    f32x4 t0 = Z, t1 = Z;
#pragma unroll 2
    for (int st = 0; st < 16; ++st) {
      bf16x8 a = ldA(rt, st);
      bf16x8 g0 = *(const bf16x8*)(gb + (c0 * 16 + st) * 512);
      bf16x8 g1 = *(const bf16x8*)(gb + ((c0 + 2) * 16 + st) * 512);
      t0 = __builtin_amdgcn_mfma_f32_16x16x32_bf16(a, g0, t0, 0, 0, 0);
      t1 = __builtin_amdgcn_mfma_f32_16x16x32_bf16(a, g1, t1, 0, 0, 0);
    }
    f32x4 P0 = park[w * 64 + lane];
    f32x4 P1 = park[(w + 8) * 64 + lane];
    float wx0 = WxL[c0 * 16 + l15];
    float wx1 = WxL[(c0 + 2) * 16 + l15];
#pragma unroll
    for (int r = 0; r < 4; ++r) {
      int row = blk * BM + rt * 16 + q * 4 + r;
      out[row * D + c0 * 16 + l15] = t0[r] + P0[r] + wx0;
      out[row * D + (c0 + 2) * 16 + l15] = t1[r] + P1[r] + wx1;
    }
  }
}

extern "C" void kernel_launch(void* const* d_in, const int* in_sizes, int n_in,
                              void* d_out, int out_size, void* d_ws, size_t ws_size,
                              hipStream_t stream) {
  const float* state = (const float*)d_in[0];
  const float* Wz0 = (const float*)d_in[1];
  const float* bz0 = (const float*)d_in[2];
  const float* Wz1 = (const float*)d_in[3];
  const float* Wz2 = (const float*)d_in[4];
  const float* Wz3 = (const float*)d_in[5];
  const float* WzL = (const float*)d_in[6];
  const float* Wx0 = (const float*)d_in[7];
  const float* bx0 = (const float*)d_in[8];
  const float* Wx1 = (const float*)d_in[9];
  const float* bx1 = (const float*)d_in[10];
  const float* Wx2 = (const float*)d_in[11];
  const float* bx2 = (const float*)d_in[12];
  const float* WxL = (const float*)d_in[13];

  if (ws_size < (size_t)WS_ELEMS * 2) {
    fill_sentinel<<<(out_size + 255) / 256, 256, 0, stream>>>((float*)d_out, out_size);
    return;
  }
  u16* wsw = (u16*)d_ws;
  prep_kernel<<<OFF_WEND / 256, 256, 0, stream>>>(Wz0, Wz1, Wz2, Wz3, Wx0, Wx1, Wx2, wsw);
  icnn_kernel<<<B_TOTAL / BM, 512, 0, stream>>>(state, bz0, bx0, bx1, bx2, WzL, WxL,
                                                wsw, (float*)d_out);
}

// Round 4
// 776.753 us; speedup vs baseline: 1.0117x; 1.0117x over previous
//
#include <hip/hip_runtime.h>

typedef unsigned short u16;
typedef unsigned int u32;
typedef unsigned long long u64;

#define B_TOTAL 65536
#define H 512
#define D 64
#define BM 128

typedef __bf16 bf16x8 __attribute__((ext_vector_type(8)));
typedef float f32x4 __attribute__((ext_vector_type(4)));

__device__ __forceinline__ u32 f2b(float f) {  // fp32 -> bf16 bits, RNE
  u32 u = __builtin_bit_cast(u32, f);
  return (u + 0x7fffu + ((u >> 16) & 1u)) >> 16;
}
__device__ __forceinline__ float b2f(u32 bits) {
  return __builtin_bit_cast(float, bits << 16);
}

// ---- workspace layout (bf16 element offsets) ----
// Weight regions are FRAGMENT-PACKED: for logical B-matrix M[NN][KK],
// packed[( (n>>4)*(KK/32) + (k>>5) )*512 + lane*8 + j] = M[n][k],
// n = ntile*16 + (lane&15), k = kstep*32 + (lane>>4)*8 + j.
#define OFF_Wz0b 0          /* [N=512][K=64]  fwd L0 */
#define OFF_Wx0b 32768
#define OFF_Wx1b 65536
#define OFF_Wx2b 98304
#define OFF_Wz1b 131072     /* [N=512][K=512] fwd */
#define OFF_Wz2b 393216
#define OFF_Wz3b 655360
#define OFF_Wz1t 917504     /* [N=512][K=512] transposed, bwd */
#define OFF_Wz2t 1179648
#define OFF_Wz3t 1441792
#define OFF_Wz0t 1703936    /* [N=64][K=512] transposed grad weights */
#define OFF_Wx0t 1736704
#define OFF_Wx1t 1769472
#define OFF_Wx2t 1802240
#define OFF_WEND 1835008
#define SLAB_ELEMS (B_TOTAL * H)          /* 33,554,432 bf16 per slab */
#define OFF_S0 OFF_WEND
#define OFF_S1 (OFF_S0 + SLAB_ELEMS)
#define OFF_S2 (OFF_S1 + SLAB_ELEMS)
#define WS_ELEMS (OFF_S2 + SLAB_ELEMS)    /* ~102.5M elems = ~205 MB */

// ---- weight prep: fp32 -> bf16, fragment-packed (+ transposed variants) ----
__global__ __launch_bounds__(256) void prep_kernel(
    const float* __restrict__ Wz0, const float* __restrict__ Wz1,
    const float* __restrict__ Wz2, const float* __restrict__ Wz3,
    const float* __restrict__ Wx0, const float* __restrict__ Wx1,
    const float* __restrict__ Wx2, u16* __restrict__ wsb) {
  int i = blockIdx.x * 256 + threadIdx.x;   // grid exactly covers OFF_WEND
  const float* src;
  int NN, KK, trans, p;
  if (i < 131072) {                          // x-path fwd: [512][64] direct
    int r = i >> 15; p = i & 32767;
    src = (r == 0) ? Wz0 : (r == 1) ? Wx0 : (r == 2) ? Wx1 : Wx2;
    NN = 512; KK = 64; trans = 0;
  } else if (i < 917504) {                   // H fwd: [512][512] direct
    int j = i - 131072; int r = j >> 18; p = j & 262143;
    src = (r == 0) ? Wz1 : (r == 1) ? Wz2 : Wz3;
    NN = 512; KK = 512; trans = 0;
  } else if (i < 1703936) {                  // H bwd: transposed
    int j = i - 917504; int r = j >> 18; p = j & 262143;
    src = (r == 0) ? Wz1 : (r == 1) ? Wz2 : Wz3;
    NN = 512; KK = 512; trans = 1;
  } else {                                   // grad weights: [64][512] = W^T
    int j = i - 1703936; int r = j >> 15; p = j & 32767;
    src = (r == 0) ? Wz0 : (r == 1) ? Wx0 : (r == 2) ? Wx1 : Wx2;
    NN = 64; KK = 512; trans = 1;
  }
  int jj = p & 7, lane = (p >> 3) & 63, blk = p >> 9;
  int kt_sh = (KK == 64) ? 1 : 4;            // log2(KK/32)
  int ntile = blk >> kt_sh;
  int kstep = blk & ((1 << kt_sh) - 1);
  int n = ntile * 16 + (lane & 15);
  int k = kstep * 32 + ((lane >> 4) << 3) + jj;
  float v = trans ? src[k * NN + n] : src[n * KK + k];
  wsb[i] = (u16)f2b(v);
}

__global__ __launch_bounds__(256) void fill_sentinel(float* out, int n) {
  int i = blockIdx.x * 256 + threadIdx.x;
  if (i < n) out[i] = 12345.0f;   // unmistakable "workspace too small" marker
}

// ---- fully-fused ICNN fwd+bwd (single GEMM kernel) ----
// ROUND-4 GEOMETRY: BM=128 rows/block, 512 blocks, 8 waves; wave w owns ALL
// 128 rows x 64 cols [w*64,+64) -> acc[8][4] = 128 acc regs. At
// __launch_bounds__(512,2) the unified budget is 256 regs/wave: acc 128 +
// working a/b ~64 + addr ~30 fits WITH slack (rounds 1-3 died fighting a
// 128-reg cap). Wins vs the 448us BM=64 baseline:
//  (1) weight L2 traffic halved (each weight frag amortized over 128 rows);
//  (2) barriers per unit work halved + per-phase MFMA doubled (512/wave);
//  (3) barriers are raw `s_waitcnt lgkmcnt(0); s_barrier` -- LDS ordering
//      only. Slab stores / weight loads are NEVER drained at barriers
//      (slab is same-thread write->read; compiler inserts per-wave vmcnt).
// LDS = zbuf[128][512] 128K + xbuf 18K = 149.5 KB, 1 block/CU. Grad park
// lives in 4 persistent f32x4 regs. All acc-indexing loops fully unrolled
// (runtime-indexed ext_vector arrays -> scratch); only st-loops are unroll-1.
__global__ __launch_bounds__(512, 2) void icnn_kernel(
    const float* __restrict__ state,
    const float* __restrict__ bz0, const float* __restrict__ bx0,
    const float* __restrict__ bx1, const float* __restrict__ bx2,
    const float* __restrict__ WzL, const float* __restrict__ WxL,
    u16* __restrict__ wsw, float* __restrict__ out) {
  __shared__ u16 zbuf[BM * H];      // XOR-swizzled activations, 128 KB
  __shared__ u16 xbuf[BM * 72];     // padded x staging, 18 KB

  const int tid = threadIdx.x;
  const int w = tid >> 6;           // 0..7
  const int lane = tid & 63;
  const int l15 = lane & 15;
  const int q = lane >> 4;
  const int blk = blockIdx.x;

  const u16* Wz0b = wsw + OFF_Wz0b;
  const u16* Wx0b = wsw + OFF_Wx0b;
  const u16* Wx1b = wsw + OFF_Wx1b;
  const u16* Wx2b = wsw + OFF_Wx2b;
  const u16* Wz1b = wsw + OFF_Wz1b;
  const u16* Wz2b = wsw + OFF_Wz2b;
  const u16* Wz3b = wsw + OFF_Wz3b;
  const u16* Wz1t = wsw + OFF_Wz1t;
  const u16* Wz2t = wsw + OFF_Wz2t;
  const u16* Wz3t = wsw + OFF_Wz3t;
  const u16* Wz0t = wsw + OFF_Wz0t;
  const u16* Wx0t = wsw + OFF_Wx0t;
  const u16* Wx1t = wsw + OFF_Wx1t;
  const u16* Wx2t = wsw + OFF_Wx2t;
  u64* slab0 = (u64*)(wsw + OFF_S0);
  u64* slab1 = (u64*)(wsw + OFF_S1);
  u64* slab2 = (u64*)(wsw + OFF_S2);

  // LDS-only barrier: drains LDS ops (visibility across waves) but lets
  // global stores/loads stay in flight across the barrier (no vmcnt(0)).
  auto lbar = [&]() {
    asm volatile("s_waitcnt lgkmcnt(0)" ::: "memory");
    __builtin_amdgcn_s_barrier();
    asm volatile("" ::: "memory");
  };

  // ---- stage x = state-1 into xbuf (bf16, padded row-major) ----
  {
#pragma unroll
    for (int ii = 0; ii < 2; ++ii) {
      int i = tid * 2 + ii;                  // 128 rows x 8 chunks of 8 floats
      int r = i >> 3, c0 = (i & 7) << 3;
      const float* p = state + (blk * BM + r) * D + c0;
      f32x4 v0 = __builtin_nontemporal_load((const f32x4*)p);
      f32x4 v1 = __builtin_nontemporal_load((const f32x4*)(p + 4));
      u32* dst = (u32*)&xbuf[r * 72 + c0];
      dst[0] = f2b(v0[0] - 1.0f) | (f2b(v0[1] - 1.0f) << 16);
      dst[1] = f2b(v0[2] - 1.0f) | (f2b(v0[3] - 1.0f) << 16);
      dst[2] = f2b(v1[0] - 1.0f) | (f2b(v1[1] - 1.0f) << 16);
      dst[3] = f2b(v1[2] - 1.0f) | (f2b(v1[3] - 1.0f) << 16);
    }
  }

  f32x4 acc[8][4];                  // 128 acc regs: 128 rows x 64 cols / wave
  const f32x4 Z = {0.f, 0.f, 0.f, 0.f};
  f32x4 pk0 = Z, pk1 = Z, pk2 = Z, pk3 = Z;  // grad park (16 regs)

  auto ldA = [&](int rt, int step) -> bf16x8 {     // LDS A-frag (swizzled)
    int m = rt * 16 + l15;
    int idx = m * H + (((step * 4 + q) ^ (m & 7)) << 3);
    return *(const bf16x8*)(&zbuf[idx]);
  };
  auto ldX = [&](int rt, int ks) -> bf16x8 {       // x A-frag from padded xbuf
    return *(const bf16x8*)(&xbuf[(rt * 16 + l15) * 72 + ks * 32 + q * 8]);
  };
  auto wrZ = [&](int row, int n, u16 bits) {       // swizzled LDS bf16 write
    zbuf[row * H + ((((n >> 3) ^ (row & 7))) << 3) + (n & 7)] = bits;
  };
  auto zeroAcc = [&]() {
#pragma unroll
    for (int mt = 0; mt < 8; ++mt)
#pragma unroll
      for (int nt = 0; nt < 4; ++nt) acc[mt][nt] = Z;
  };

  // acc += zbuf @ W^T (K=512), all 128 rows. Weights stream global->VGPR.
  // st-loop unroll-1 (acc indices static inside); compiler pipelines loads.
  auto fwdH = [&](const u16* Wp) {
    const u16* wb = Wp + (w * 64) * 512 + lane * 8;  // wave's 64-col strip
#pragma unroll 1
    for (int st = 0; st < 16; ++st) {
      bf16x8 b[4];
#pragma unroll
      for (int nt = 0; nt < 4; ++nt)
        b[nt] = *(const bf16x8*)(wb + (nt * 16 + st) * 512);
      bf16x8 a0[4];
#pragma unroll
      for (int mt = 0; mt < 4; ++mt) a0[mt] = ldA(mt, st);
#pragma unroll
      for (int nt = 0; nt < 4; ++nt)
#pragma unroll
        for (int mt = 0; mt < 4; ++mt)
          acc[mt][nt] = __builtin_amdgcn_mfma_f32_16x16x32_bf16(a0[mt], b[nt],
                                                                acc[mt][nt], 0, 0, 0);
      bf16x8 a1[4];
#pragma unroll
      for (int mt = 0; mt < 4; ++mt) a1[mt] = ldA(4 + mt, st);
#pragma unroll
      for (int nt = 0; nt < 4; ++nt)
#pragma unroll
        for (int mt = 0; mt < 4; ++mt)
          acc[4 + mt][nt] = __builtin_amdgcn_mfma_f32_16x16x32_bf16(a1[mt], b[nt],
                                                                    acc[4 + mt][nt], 0, 0, 0);
    }
  };

  // acc += x @ Wx^T (K=64), all 128 rows.
  auto fwdX = [&](const u16* Wxp) {
    const u16* xb = Wxp + lane * 8;
#pragma unroll
    for (int ks = 0; ks < 2; ++ks) {
      bf16x8 b4[4];
#pragma unroll
      for (int nt = 0; nt < 4; ++nt)
        b4[nt] = *(const bf16x8*)(xb + ((w * 4 + nt) * 2 + ks) * 512);
#pragma unroll
      for (int mt = 0; mt < 8; ++mt) {
        bf16x8 ax = ldX(mt, ks);
#pragma unroll
        for (int nt = 0; nt < 4; ++nt)
          acc[mt][nt] = __builtin_amdgcn_mfma_f32_16x16x32_bf16(ax, b4[nt],
                                                                acc[mt][nt], 0, 0, 0);
      }
    }
  };

  // forward epilogue: a+=bias; z=softplus -> zbuf; s=sigmoid -> slab
  auto fwd_epi = [&](const float* biasp, u64* slab) {
    float bias[4];
#pragma unroll
    for (int nt = 0; nt < 4; ++nt) bias[nt] = biasp[(w * 4 + nt) * 16 + l15];
#pragma unroll
    for (int mt = 0; mt < 8; ++mt)
#pragma unroll
      for (int nt = 0; nt < 4; ++nt) {
        int n = (w * 4 + nt) * 16 + l15;
        f32x4 A = acc[mt][nt];
        u64 pack = 0;
#pragma unroll
        for (int r = 0; r < 4; ++r) {
          float a = A[r] + bias[nt];
          float t = __expf(-a);
          float u = 1.0f + t;
          float s = __builtin_amdgcn_rcpf(u);     // sigmoid(a)
          float z = a + __logf(u);                // softplus(a)
          pack |= (u64)f2b(s) << (16 * r);
          wrZ(mt * 16 + q * 4 + r, n, (u16)f2b(z));
        }
        slab[((blk * 8 + w) * 32 + mt * 4 + nt) * 64 + lane] = pack;
      }
  };
  auto d3_epi = [&](const float* biasp) {   // d3 = WzL * sigmoid(a3) -> zbuf
    float bias[4], wl[4];
#pragma unroll
    for (int nt = 0; nt < 4; ++nt) {
      bias[nt] = biasp[(w * 4 + nt) * 16 + l15];
      wl[nt] = WzL[(w * 4 + nt) * 16 + l15];
    }
#pragma unroll
    for (int mt = 0; mt < 8; ++mt)
#pragma unroll
      for (int nt = 0; nt < 4; ++nt) {
        int n = (w * 4 + nt) * 16 + l15;
        f32x4 A = acc[mt][nt];
#pragma unroll
        for (int r = 0; r < 4; ++r) {
          float a = A[r] + bias[nt];
          float t = __expf(-a);
          float s = __builtin_amdgcn_rcpf(1.0f + t);
          wrZ(mt * 16 + q * 4 + r, n, (u16)f2b(wl[nt] * s));
        }
      }
  };
  // d = g * s -> zbuf (slab read once, same thread that wrote it)
  auto bwd_epi = [&](const u64* slab) {
#pragma unroll
    for (int mt = 0; mt < 8; ++mt) {
      u64 v[4];
#pragma unroll
      for (int nt = 0; nt < 4; ++nt)
        v[nt] = slab[((blk * 8 + w) * 32 + mt * 4 + nt) * 64 + lane];
#pragma unroll
      for (int nt = 0; nt < 4; ++nt) {
        int n = (w * 4 + nt) * 16 + l15;
        f32x4 A = acc[mt][nt];
#pragma unroll
        for (int r = 0; r < 4; ++r) {
          float s = b2f((u32)(v[nt] >> (16 * r)) & 0xffffu);
          wrZ(mt * 16 + q * 4 + r, n, (u16)f2b(A[r] * s));
        }
      }
    }
  };

  // grad mini-phase: pk += zbuf(d) @ Wg (main acc is DEAD here).
  // Wave w owns row-tile w (rows w*16..+16), all 4 col-tiles of the 64 cols.
  auto minigrad = [&](const u16* Wg) {
    const u16* gb = Wg + lane * 8;
    f32x4 t0 = pk0, t1 = pk1, t2 = pk2, t3 = pk3;
#pragma unroll 1
    for (int st = 0; st < 16; ++st) {
      bf16x8 a = ldA(w, st);
      bf16x8 g0 = *(const bf16x8*)(gb + (0 * 16 + st) * 512);
      bf16x8 g1 = *(const bf16x8*)(gb + (1 * 16 + st) * 512);
      bf16x8 g2 = *(const bf16x8*)(gb + (2 * 16 + st) * 512);
      bf16x8 g3 = *(const bf16x8*)(gb + (3 * 16 + st) * 512);
      t0 = __builtin_amdgcn_mfma_f32_16x16x32_bf16(a, g0, t0, 0, 0, 0);
      t1 = __builtin_amdgcn_mfma_f32_16x16x32_bf16(a, g1, t1, 0, 0, 0);
      t2 = __builtin_amdgcn_mfma_f32_16x16x32_bf16(a, g2, t2, 0, 0, 0);
      t3 = __builtin_amdgcn_mfma_f32_16x16x32_bf16(a, g3, t3, 0, 0, 0);
    }
    pk0 = t0; pk1 = t1; pk2 = t2; pk3 = t3;
  };

  // ---------------- forward ----------------
  lbar();                                   // xbuf ready
  zeroAcc(); fwdX(Wz0b);                    // a0 = x@Wz0^T
  fwd_epi(bz0, slab0);                      // z0 -> zbuf (no prior readers)
  lbar();                                   // z0 visible
  zeroAcc(); fwdH(Wz1b); fwdX(Wx0b);        // a1 = z0@Wz1^T + x@Wx0^T
  lbar();                                   // all z0 reads done
  fwd_epi(bx0, slab1);                      // z1 -> zbuf
  lbar();
  zeroAcc(); fwdH(Wz2b); fwdX(Wx1b);
  lbar();
  fwd_epi(bx1, slab2);                      // z2 -> zbuf
  lbar();
  zeroAcc(); fwdH(Wz3b); fwdX(Wx2b);        // a3 (last use of xbuf)
  lbar();
  d3_epi(bx2);                              // d3 -> zbuf
  lbar();
  // ---------------- backward ----------------
  minigrad(Wx2t);                           // pk  = d3@Wx2t
  zeroAcc(); fwdH(Wz3t);                    // acc = d3@Wz3
  lbar();
  bwd_epi(slab2);                           // d2 -> zbuf
  lbar();
  minigrad(Wx1t);                           // pk += d2@Wx1t
  zeroAcc(); fwdH(Wz2t);                    // acc = d2@Wz2
  lbar();
  bwd_epi(slab1);                           // d1 -> zbuf
  lbar();
  minigrad(Wx0t);                           // pk += d1@Wx0t
  zeroAcc(); fwdH(Wz1t);                    // acc = d1@Wz1
  lbar();
  bwd_epi(slab0);                           // d0 -> zbuf
  lbar();
  // ---- final: out = d0@Wz0t + pk + WxL ----
  minigrad(Wz0t);                           // pk += d0@Wz0t
  {
    f32x4 pks[4] = {pk0, pk1, pk2, pk3};    // static-indexed via full unroll
#pragma unroll
    for (int ct = 0; ct < 4; ++ct) {
      float wx = WxL[ct * 16 + l15];
#pragma unroll
      for (int r = 0; r < 4; ++r) {
        int row = blk * BM + w * 16 + q * 4 + r;
        __builtin_nontemporal_store(pks[ct][r] + wx, &out[row * D + ct * 16 + l15]);
      }
    }
  }
}

extern "C" void kernel_launch(void* const* d_in, const int* in_sizes, int n_in,
                              void* d_out, int out_size, void* d_ws, size_t ws_size,
                              hipStream_t stream) {
  const float* state = (const float*)d_in[0];
  const float* Wz0 = (const float*)d_in[1];
  const float* bz0 = (const float*)d_in[2];
  const float* Wz1 = (const float*)d_in[3];
  const float* Wz2 = (const float*)d_in[4];
  const float* Wz3 = (const float*)d_in[5];
  const float* WzL = (const float*)d_in[6];
  const float* Wx0 = (const float*)d_in[7];
  const float* bx0 = (const float*)d_in[8];
  const float* Wx1 = (const float*)d_in[9];
  const float* bx1 = (const float*)d_in[10];
  const float* Wx2 = (const float*)d_in[11];
  const float* bx2 = (const float*)d_in[12];
  const float* WxL = (const float*)d_in[13];

  if (ws_size < (size_t)WS_ELEMS * 2) {
    fill_sentinel<<<(out_size + 255) / 256, 256, 0, stream>>>((float*)d_out, out_size);
    return;
  }
  u16* wsw = (u16*)d_ws;
  prep_kernel<<<OFF_WEND / 256, 256, 0, stream>>>(Wz0, Wz1, Wz2, Wz3, Wx0, Wx1, Wx2, wsw);
  icnn_kernel<<<B_TOTAL / BM, 512, 0, stream>>>(state, bz0, bx0, bx1, bx2, WzL, WxL,
                                                wsw, (float*)d_out);
}

// Round 5
// 547.650 us; speedup vs baseline: 1.4349x; 1.4183x over previous
//
#include <hip/hip_runtime.h>

typedef unsigned short u16;
typedef unsigned int u32;
typedef unsigned long long u64;

#define B_TOTAL 65536
#define H 512
#define D 64
#define BM 64

typedef __bf16 bf16x8 __attribute__((ext_vector_type(8)));
typedef float f32x4 __attribute__((ext_vector_type(4)));

__device__ __forceinline__ u32 f2b(float f) {  // fp32 -> bf16 bits, RNE
  u32 u = __builtin_bit_cast(u32, f);
  return (u + 0x7fffu + ((u >> 16) & 1u)) >> 16;
}
__device__ __forceinline__ float b2f(u32 bits) {
  return __builtin_bit_cast(float, bits << 16);
}

// ---- workspace layout (bf16 element offsets) ----
// Weight regions are FRAGMENT-PACKED: for logical B-matrix M[NN][KK],
// packed[( (n>>4)*(KK/32) + (k>>5) )*512 + lane*8 + j] = M[n][k],
// n = ntile*16 + (lane&15), k = kstep*32 + (lane>>4)*8 + j.
#define OFF_Wz0b 0          /* [N=512][K=64]  fwd L0 */
#define OFF_Wx0b 32768
#define OFF_Wx1b 65536
#define OFF_Wx2b 98304
#define OFF_Wz1b 131072     /* [N=512][K=512] fwd */
#define OFF_Wz2b 393216
#define OFF_Wz3b 655360
#define OFF_Wz1t 917504     /* [N=512][K=512] transposed, bwd */
#define OFF_Wz2t 1179648
#define OFF_Wz3t 1441792
#define OFF_Wz0t 1703936    /* [N=64][K=512] transposed grad weights */
#define OFF_Wx0t 1736704
#define OFF_Wx1t 1769472
#define OFF_Wx2t 1802240
#define OFF_WEND 1835008
#define SLAB_ELEMS (B_TOTAL * H)          /* 33,554,432 bf16 per slab */
#define OFF_S0 OFF_WEND
#define OFF_S1 (OFF_S0 + SLAB_ELEMS)
#define OFF_S2 (OFF_S1 + SLAB_ELEMS)
#define WS_ELEMS (OFF_S2 + SLAB_ELEMS)    /* ~102.5M elems = ~205 MB */

// ---- weight prep: fp32 -> bf16, fragment-packed (+ transposed variants) ----
__global__ __launch_bounds__(256) void prep_kernel(
    const float* __restrict__ Wz0, const float* __restrict__ Wz1,
    const float* __restrict__ Wz2, const float* __restrict__ Wz3,
    const float* __restrict__ Wx0, const float* __restrict__ Wx1,
    const float* __restrict__ Wx2, u16* __restrict__ wsb) {
  int i = blockIdx.x * 256 + threadIdx.x;   // grid exactly covers OFF_WEND
  const float* src;
  int NN, KK, trans, p;
  if (i < 131072) {                          // x-path fwd: [512][64] direct
    int r = i >> 15; p = i & 32767;
    src = (r == 0) ? Wz0 : (r == 1) ? Wx0 : (r == 2) ? Wx1 : Wx2;
    NN = 512; KK = 64; trans = 0;
  } else if (i < 917504) {                   // H fwd: [512][512] direct
    int j = i - 131072; int r = j >> 18; p = j & 262143;
    src = (r == 0) ? Wz1 : (r == 1) ? Wz2 : Wz3;
    NN = 512; KK = 512; trans = 0;
  } else if (i < 1703936) {                  // H bwd: transposed
    int j = i - 917504; int r = j >> 18; p = j & 262143;
    src = (r == 0) ? Wz1 : (r == 1) ? Wz2 : Wz3;
    NN = 512; KK = 512; trans = 1;
  } else {                                   // grad weights: [64][512] = W^T
    int j = i - 1703936; int r = j >> 15; p = j & 32767;
    src = (r == 0) ? Wz0 : (r == 1) ? Wx0 : (r == 2) ? Wx1 : Wx2;
    NN = 64; KK = 512; trans = 1;
  }
  int jj = p & 7, lane = (p >> 3) & 63, blk = p >> 9;
  int kt_sh = (KK == 64) ? 1 : 4;            // log2(KK/32)
  int ntile = blk >> kt_sh;
  int kstep = blk & ((1 << kt_sh) - 1);
  int n = ntile * 16 + (lane & 15);
  int k = kstep * 32 + ((lane >> 4) << 3) + jj;
  float v = trans ? src[k * NN + n] : src[n * KK + k];
  wsb[i] = (u16)f2b(v);
}

__global__ __launch_bounds__(256) void fill_sentinel(float* out, int n) {
  int i = blockIdx.x * 256 + threadIdx.x;
  if (i < n) out[i] = 12345.0f;   // unmistakable "workspace too small" marker
}

// ---- fully-fused ICNN fwd+bwd (single GEMM kernel) ----
// ROUND-5: R0's proven structure (BM=64, LDS-staged weights via
// global_load_lds + per-wave vmcnt double-buffer) with DOUBLED wave count:
// 1024 thr = 16 waves; wave w owns cols [w*32,+32) -> acc[4][2] = 32 acc
// regs. 4 waves/SIMD (occupancy 23%->~47%) hides ds_read/DMA/trans latency
// that R0's 2 waves/SIMD could not. Fits the mandatory 128-reg cap
// ((1024,4)) because weights live in LDS, not VGPRs (rounds 1-2's spill
// trap), and acc halved. Park = single f32x4 reg/wave (16 tiles, 16 waves).
// Barriers are LDS-only (lgkmcnt(0)+s_barrier, validated R4): slab stores
// and weight DMAs are never drained at phase boundaries.
// LDS = zbuf 64K + wbuf 64K + xbuf 9.2K = 137.2 KB, 1 block/CU.
__global__ __launch_bounds__(1024, 4) void icnn_kernel(
    const float* __restrict__ state,
    const float* __restrict__ bz0, const float* __restrict__ bx0,
    const float* __restrict__ bx1, const float* __restrict__ bx2,
    const float* __restrict__ WzL, const float* __restrict__ WxL,
    u16* __restrict__ wsw, float* __restrict__ out) {
  __shared__ u16 zbuf[BM * H];      // XOR-swizzled activations, 64 KB
  __shared__ u16 wbuf[2 * 16384];   // double-buffered weight K-slices, 64 KB
  __shared__ u16 xbuf[BM * 72];     // padded x staging, 9.2 KB

  const int tid = threadIdx.x;
  const int w = tid >> 6;           // 0..15
  const int lane = tid & 63;
  const int l15 = lane & 15;
  const int q = lane >> 4;
  const int blk = blockIdx.x;

  const u16* Wz0b = wsw + OFF_Wz0b;
  const u16* Wx0b = wsw + OFF_Wx0b;
  const u16* Wx1b = wsw + OFF_Wx1b;
  const u16* Wx2b = wsw + OFF_Wx2b;
  const u16* Wz1b = wsw + OFF_Wz1b;
  const u16* Wz2b = wsw + OFF_Wz2b;
  const u16* Wz3b = wsw + OFF_Wz3b;
  const u16* Wz1t = wsw + OFF_Wz1t;
  const u16* Wz2t = wsw + OFF_Wz2t;
  const u16* Wz3t = wsw + OFF_Wz3t;
  const u16* Wz0t = wsw + OFF_Wz0t;
  const u16* Wx0t = wsw + OFF_Wx0t;
  const u16* Wx1t = wsw + OFF_Wx1t;
  const u16* Wx2t = wsw + OFF_Wx2t;
  u64* slab0 = (u64*)(wsw + OFF_S0);
  u64* slab1 = (u64*)(wsw + OFF_S1);
  u64* slab2 = (u64*)(wsw + OFF_S2);

  // LDS-only barrier: orders zbuf ds ops across waves; global stores and
  // weight DMAs (vmcnt) stay in flight. wbuf is per-wave private (own DMAs,
  // own reads, vmcnt-disciplined) so it needs no cross-wave ordering.
  auto lbar = [&]() {
    asm volatile("s_waitcnt lgkmcnt(0)" ::: "memory");
    __builtin_amdgcn_s_barrier();
    asm volatile("" ::: "memory");
  };

  // ---- stage x = state-1 into xbuf (bf16, padded row-major) ----
  {
    int r = tid >> 4, c0 = (tid & 15) << 2;  // 64 rows x 16 chunks of 4 floats
    const float* p = state + (blk * BM + r) * D + c0;
    f32x4 v = __builtin_nontemporal_load((const f32x4*)p);
    u32* dst = (u32*)&xbuf[r * 72 + c0];
    dst[0] = f2b(v[0] - 1.0f) | (f2b(v[1] - 1.0f) << 16);
    dst[1] = f2b(v[2] - 1.0f) | (f2b(v[3] - 1.0f) << 16);
  }

  f32x4 acc[4][2];                  // 32 acc regs: 64 rows x 32 cols / wave
  const f32x4 Z = {0.f, 0.f, 0.f, 0.f};
  f32x4 pk = Z;                     // grad park: wave's single 16x16 out tile

  auto ldA = [&](int mt, int step) -> bf16x8 {     // LDS A-frag (swizzled)
    int m = mt * 16 + l15;
    int idx = m * H + (((step * 4 + q) ^ (m & 7)) << 3);
    return *(const bf16x8*)(&zbuf[idx]);
  };
  auto ldX = [&](int mt, int ks) -> bf16x8 {       // x A-frag from padded xbuf
    return *(const bf16x8*)(&xbuf[(mt * 16 + l15) * 72 + ks * 32 + q * 8]);
  };
  auto wrZ = [&](int row, int n, u16 bits) {       // swizzled LDS bf16 write
    zbuf[row * H + ((((n >> 3) ^ (row & 7))) << 3) + (n & 7)] = bits;
  };

  // DMA one K-step slice (this wave's 2 chunks, 2 KB) into wbuf[buf].
  auto stageW = [&](const u16* Wp, int st, int buf) {
    const u16* gb = Wp + ((w * 2) * 16 + st) * 512 + lane * 8;
    u16* lb = &wbuf[buf * 16384 + (w * 2) * 512];
#pragma unroll
    for (int j = 0; j < 2; ++j)
      __builtin_amdgcn_global_load_lds(
          (const __attribute__((address_space(1))) void*)(gb + j * 16 * 512),
          (__attribute__((address_space(3))) void*)(lb + j * 512), 16, 0, 0);
  };

  // acc (+)= x @ Wx^T (K=64). zero_first: overwrite acc on ks==0.
  auto fwdX = [&](const u16* Wxp, bool zero_first) {
    const u16* xb = Wxp + lane * 8;
#pragma unroll
    for (int ks = 0; ks < 2; ++ks) {
      bf16x8 b2[2];
#pragma unroll
      for (int nt = 0; nt < 2; ++nt)
        b2[nt] = *(const bf16x8*)(xb + ((w * 2 + nt) * 2 + ks) * 512);
#pragma unroll
      for (int mt = 0; mt < 4; ++mt) {
        bf16x8 ax = ldX(mt, ks);
#pragma unroll
        for (int nt = 0; nt < 2; ++nt) {
          f32x4 c = (zero_first && ks == 0) ? Z : acc[mt][nt];
          acc[mt][nt] = __builtin_amdgcn_mfma_f32_16x16x32_bf16(ax, b2[nt], c, 0, 0, 0);
        }
      }
    }
  };

  // acc = zbuf @ W^T (K=512), zero-start. Contract: step 0 already staged
  // into wbuf[0] by the caller. Per-wave vmcnt(2) waits only the PREVIOUS
  // step's 2 DMAs (conservative w.r.t. interleaved stores: still correct).
  auto fwdH = [&](const u16* Wp) {
#pragma unroll
    for (int st = 0; st < 16; ++st) {
      if (st < 15) {
        stageW(Wp, st + 1, (st + 1) & 1);
        asm volatile("s_waitcnt vmcnt(2)" ::: "memory");  // prev step's DMAs done
      } else {
        asm volatile("s_waitcnt vmcnt(0)" ::: "memory");
      }
      const u16* wb = &wbuf[(st & 1) * 16384 + (w * 2) * 512 + lane * 8];
      bf16x8 a[4];
#pragma unroll
      for (int mt = 0; mt < 4; ++mt) a[mt] = ldA(mt, st);
#pragma unroll
      for (int nt = 0; nt < 2; ++nt) {
        bf16x8 b = *(const bf16x8*)(wb + nt * 512);
#pragma unroll
        for (int mt = 0; mt < 4; ++mt)
          acc[mt][nt] = __builtin_amdgcn_mfma_f32_16x16x32_bf16(
              a[mt], b, (st == 0) ? Z : acc[mt][nt], 0, 0, 0);
      }
    }
  };

  // forward epilogue: a+=bias; z=softplus -> zbuf; s=sigmoid -> slab
  auto fwd_epi = [&](const float* biasp, u64* slab) {
    float bias[2];
#pragma unroll
    for (int nt = 0; nt < 2; ++nt) bias[nt] = biasp[(w * 2 + nt) * 16 + l15];
#pragma unroll
    for (int mt = 0; mt < 4; ++mt)
#pragma unroll
      for (int nt = 0; nt < 2; ++nt) {
        int n = (w * 2 + nt) * 16 + l15;
        f32x4 A = acc[mt][nt];
        u64 pack = 0;
#pragma unroll
        for (int r = 0; r < 4; ++r) {
          float a = A[r] + bias[nt];
          float t = __expf(-a);
          float u = 1.0f + t;
          float s = __builtin_amdgcn_rcpf(u);     // sigmoid(a)
          float z = a + __logf(u);                // softplus(a)
          pack |= (u64)f2b(s) << (16 * r);
          wrZ(mt * 16 + q * 4 + r, n, (u16)f2b(z));
        }
        slab[((blk * 16 + w) * 8 + mt * 2 + nt) * 64 + lane] = pack;
      }
  };
  auto d3_epi = [&](const float* biasp) {   // d3 = WzL * sigmoid(a3) -> zbuf
    float bias[2], wl[2];
#pragma unroll
    for (int nt = 0; nt < 2; ++nt) {
      bias[nt] = biasp[(w * 2 + nt) * 16 + l15];
      wl[nt] = WzL[(w * 2 + nt) * 16 + l15];
    }
#pragma unroll
    for (int mt = 0; mt < 4; ++mt)
#pragma unroll
      for (int nt = 0; nt < 2; ++nt) {
        int n = (w * 2 + nt) * 16 + l15;
        f32x4 A = acc[mt][nt];
#pragma unroll
        for (int r = 0; r < 4; ++r) {
          float a = A[r] + bias[nt];
          float t = __expf(-a);
          float s = __builtin_amdgcn_rcpf(1.0f + t);
          wrZ(mt * 16 + q * 4 + r, n, (u16)f2b(wl[nt] * s));
        }
      }
  };
  // d = g * s -> zbuf (slab read once, same thread that wrote it)
  auto bwd_epi = [&](const u64* slab) {
    u64 v[4][2];
#pragma unroll
    for (int mt = 0; mt < 4; ++mt)
#pragma unroll
      for (int nt = 0; nt < 2; ++nt)
        v[mt][nt] = slab[((blk * 16 + w) * 8 + mt * 2 + nt) * 64 + lane];
#pragma unroll
    for (int mt = 0; mt < 4; ++mt)
#pragma unroll
      for (int nt = 0; nt < 2; ++nt) {
        int n = (w * 2 + nt) * 16 + l15;
        f32x4 A = acc[mt][nt];
#pragma unroll
        for (int r = 0; r < 4; ++r) {
          float s = b2f((u32)(v[mt][nt] >> (16 * r)) & 0xffffu);
          wrZ(mt * 16 + q * 4 + r, n, (u16)f2b(A[r] * s));
        }
      }
  };

  // grad mini-phase: pk += zbuf(d) @ Wg (main acc is DEAD here).
  // 16 waves <-> 16 out tiles: wave w owns tile (rt=w&3, ct=w>>2).
  auto minigrad = [&](const u16* Wg, bool init) {
    int rt = w & 3, ct = w >> 2;
    const u16* gb = Wg + lane * 8;
    f32x4 t = init ? Z : pk;
#pragma unroll
    for (int st = 0; st < 16; ++st) {
      bf16x8 a = ldA(rt, st);
      bf16x8 g = *(const bf16x8*)(gb + (ct * 16 + st) * 512);
      t = __builtin_amdgcn_mfma_f32_16x16x32_bf16(a, g, t, 0, 0, 0);
    }
    pk = t;
  };

  // ---------------- forward ----------------
  lbar();                                   // xbuf ready
  fwdX(Wz0b, true);                         // a0 = x@Wz0^T
  stageW(Wz1b, 0, 0);                       // prestage; overlaps epilogue
  fwd_epi(bz0, slab0);
  lbar();
  fwdH(Wz1b); fwdX(Wx0b, false);            // a1 = z0@Wz1^T + x@Wx0^T
  lbar();
  stageW(Wz2b, 0, 0);
  fwd_epi(bx0, slab1);
  lbar();
  fwdH(Wz2b); fwdX(Wx1b, false);
  lbar();
  stageW(Wz3b, 0, 0);
  fwd_epi(bx1, slab2);
  lbar();
  fwdH(Wz3b); fwdX(Wx2b, false);            // a3 (last use of xbuf)
  lbar();
  stageW(Wz3t, 0, 0);                       // prestage bwd chain
  d3_epi(bx2);                              // d3 -> zbuf
  lbar();
  // ---------------- backward ----------------
  minigrad(Wx2t, true);                     // pk  = d3@Wx2t
  fwdH(Wz3t);                               // acc = d3@Wz3
  lbar();
  stageW(Wz2t, 0, 0);
  bwd_epi(slab2);                           // d2 -> zbuf
  lbar();
  minigrad(Wx1t, false);                    // pk += d2@Wx1t
  fwdH(Wz2t);                               // acc = d2@Wz2
  lbar();
  stageW(Wz1t, 0, 0);
  bwd_epi(slab1);                           // d1 -> zbuf
  lbar();
  minigrad(Wx0t, false);                    // pk += d1@Wx0t
  fwdH(Wz1t);                               // acc = d1@Wz1
  lbar();
  bwd_epi(slab0);                           // d0 -> zbuf
  lbar();
  // ---- final: out = d0@Wz0t + pk + WxL ----
  minigrad(Wz0t, false);                    // pk += d0@Wz0t
  {
    int rt = w & 3, ct = w >> 2;
    float wx = WxL[ct * 16 + l15];
#pragma unroll
    for (int r = 0; r < 4; ++r) {
      int row = blk * BM + rt * 16 + q * 4 + r;
      out[row * D + ct * 16 + l15] = pk[r] + wx;
    }
  }
}

extern "C" void kernel_launch(void* const* d_in, const int* in_sizes, int n_in,
                              void* d_out, int out_size, void* d_ws, size_t ws_size,
                              hipStream_t stream) {
  const float* state = (const float*)d_in[0];
  const float* Wz0 = (const float*)d_in[1];
  const float* bz0 = (const float*)d_in[2];
  const float* Wz1 = (const float*)d_in[3];
  const float* Wz2 = (const float*)d_in[4];
  const float* Wz3 = (const float*)d_in[5];
  const float* WzL = (const float*)d_in[6];
  const float* Wx0 = (const float*)d_in[7];
  const float* bx0 = (const float*)d_in[8];
  const float* Wx1 = (const float*)d_in[9];
  const float* bx1 = (const float*)d_in[10];
  const float* Wx2 = (const float*)d_in[11];
  const float* bx2 = (const float*)d_in[12];
  const float* WxL = (const float*)d_in[13];

  if (ws_size < (size_t)WS_ELEMS * 2) {
    fill_sentinel<<<(out_size + 255) / 256, 256, 0, stream>>>((float*)d_out, out_size);
    return;
  }
  u16* wsw = (u16*)d_ws;
  prep_kernel<<<OFF_WEND / 256, 256, 0, stream>>>(Wz0, Wz1, Wz2, Wz3, Wx0, Wx1, Wx2, wsw);
  icnn_kernel<<<B_TOTAL / BM, 1024, 0, stream>>>(state, bz0, bx0, bx1, bx2, WzL, WxL,
                                                 wsw, (float*)d_out);
}

// Round 7
// 494.170 us; speedup vs baseline: 1.5902x; 1.1082x over previous
//
#include <hip/hip_runtime.h>

typedef unsigned short u16;
typedef unsigned int u32;
typedef unsigned long long u64;

#define B_TOTAL 65536
#define H 512
#define D 64
#define BM 64

typedef __bf16 bf16x8 __attribute__((ext_vector_type(8)));
typedef float f32x4 __attribute__((ext_vector_type(4)));

__device__ __forceinline__ u32 f2b(float f) {  // fp32 -> bf16 bits, RNE
  u32 u = __builtin_bit_cast(u32, f);
  return (u + 0x7fffu + ((u >> 16) & 1u)) >> 16;
}
__device__ __forceinline__ float b2f(u32 bits) {
  return __builtin_bit_cast(float, bits << 16);
}

// ---- workspace layout (bf16 element offsets) ----
// Weight regions are FRAGMENT-PACKED: for logical B-matrix M[NN][KK],
// packed[( (n>>4)*(KK/32) + (k>>5) )*512 + lane*8 + j] = M[n][k],
// n = ntile*16 + (lane&15), k = kstep*32 + (lane>>4)*8 + j.
#define OFF_Wz0b 0          /* [N=512][K=64]  fwd L0 */
#define OFF_Wx0b 32768
#define OFF_Wx1b 65536
#define OFF_Wx2b 98304
#define OFF_Wz1b 131072     /* [N=512][K=512] fwd */
#define OFF_Wz2b 393216
#define OFF_Wz3b 655360
#define OFF_Wz1t 917504     /* [N=512][K=512] transposed, bwd */
#define OFF_Wz2t 1179648
#define OFF_Wz3t 1441792
#define OFF_Wz0t 1703936    /* [N=64][K=512] transposed grad weights */
#define OFF_Wx0t 1736704
#define OFF_Wx1t 1769472
#define OFF_Wx2t 1802240
#define OFF_WEND 1835008
#define SLAB_ELEMS (B_TOTAL * H)          /* 33,554,432 bf16 per slab */
#define OFF_S0 OFF_WEND
#define OFF_S1 (OFF_S0 + SLAB_ELEMS)
#define OFF_S2 (OFF_S1 + SLAB_ELEMS)
#define WS_ELEMS (OFF_S2 + SLAB_ELEMS)    /* ~102.5M elems = ~205 MB */

// ---- weight prep: fp32 -> bf16, fragment-packed (+ transposed variants) ----
__global__ __launch_bounds__(256) void prep_kernel(
    const float* __restrict__ Wz0, const float* __restrict__ Wz1,
    const float* __restrict__ Wz2, const float* __restrict__ Wz3,
    const float* __restrict__ Wx0, const float* __restrict__ Wx1,
    const float* __restrict__ Wx2, u16* __restrict__ wsb) {
  int i = blockIdx.x * 256 + threadIdx.x;   // grid exactly covers OFF_WEND
  const float* src;
  int NN, KK, trans, p;
  if (i < 131072) {                          // x-path fwd: [512][64] direct
    int r = i >> 15; p = i & 32767;
    src = (r == 0) ? Wz0 : (r == 1) ? Wx0 : (r == 2) ? Wx1 : Wx2;
    NN = 512; KK = 64; trans = 0;
  } else if (i < 917504) {                   // H fwd: [512][512] direct
    int j = i - 131072; int r = j >> 18; p = j & 262143;
    src = (r == 0) ? Wz1 : (r == 1) ? Wz2 : Wz3;
    NN = 512; KK = 512; trans = 0;
  } else if (i < 1703936) {                  // H bwd: transposed
    int j = i - 917504; int r = j >> 18; p = j & 262143;
    src = (r == 0) ? Wz1 : (r == 1) ? Wz2 : Wz3;
    NN = 512; KK = 512; trans = 1;
  } else {                                   // grad weights: [64][512] = W^T
    int j = i - 1703936; int r = j >> 15; p = j & 32767;
    src = (r == 0) ? Wz0 : (r == 1) ? Wx0 : (r == 2) ? Wx1 : Wx2;
    NN = 64; KK = 512; trans = 1;
  }
  int jj = p & 7, lane = (p >> 3) & 63, blk = p >> 9;
  int kt_sh = (KK == 64) ? 1 : 4;            // log2(KK/32)
  int ntile = blk >> kt_sh;
  int kstep = blk & ((1 << kt_sh) - 1);
  int n = ntile * 16 + (lane & 15);
  int k = kstep * 32 + ((lane >> 4) << 3) + jj;
  float v = trans ? src[k * NN + n] : src[n * KK + k];
  wsb[i] = (u16)f2b(v);
}

__global__ __launch_bounds__(256) void fill_sentinel(float* out, int n) {
  int i = blockIdx.x * 256 + threadIdx.x;
  if (i < n) out[i] = 12345.0f;   // unmistakable "workspace too small" marker
}

// ---- fully-fused ICNN fwd+bwd (single GEMM kernel) ----
// ROUND-7 = ROUND-5 (correct, 514us) + two isolated fixes:
//  (1) K-MAJOR zbuf layout: z[row][col] at
//        ((col>>5)*4+(row>>4))*512 + ((col>>3)&3)*128 + (row&15)*8 + (col&7)
//      ldA is one contiguous 1KB burst/wave (sequential banks, zero
//      conflicts by construction). R5's SQ_LDS_BANK_CONFLICT was exactly
//      2x R0 and ldA count was the only doubled term -> conflicts lived in
//      the old XOR-swizzle A-read. Conflict load moves to the 16x smaller
//      write path.
//  (2) minigrad unroll capped at 4: full unroll hoisted 16 g-frags
//      (64 VGPRs) under the hard 128-reg cap of 1024-thr blocks -> spills
//      (+0.65 GB traffic in R5).
// Ownership stays R5 col-split (wave w: cols [w*32,+32), acc[4][2]) because
// it keeps wbuf staging per-wave PRIVATE -- the counted vmcnt(2) pipeline is
// only sound when a wave reads exactly the slots it staged (R6's row-split
// read sibling-staged slots -> race -> wrong results). LDS volume per step
// is identical either way (6KB/wave).
// 16 waves = 4 waves/SIMD occupancy; LDS-only barriers (lgkmcnt+s_barrier).
__global__ __launch_bounds__(1024, 4) void icnn_kernel(
    const float* __restrict__ state,
    const float* __restrict__ bz0, const float* __restrict__ bx0,
    const float* __restrict__ bx1, const float* __restrict__ bx2,
    const float* __restrict__ WzL, const float* __restrict__ WxL,
    u16* __restrict__ wsw, float* __restrict__ out) {
  __shared__ u16 zbuf[BM * H];      // K-major activations, 64 KB
  __shared__ u16 wbuf[2 * 16384];   // double-buffered weight K-slices, 64 KB
  __shared__ u16 xbuf[BM * 72];     // padded x staging, 9.2 KB

  const int tid = threadIdx.x;
  const int w = tid >> 6;           // 0..15
  const int lane = tid & 63;
  const int l15 = lane & 15;
  const int q = lane >> 4;
  const int blk = blockIdx.x;

  const u16* Wz0b = wsw + OFF_Wz0b;
  const u16* Wx0b = wsw + OFF_Wx0b;
  const u16* Wx1b = wsw + OFF_Wx1b;
  const u16* Wx2b = wsw + OFF_Wx2b;
  const u16* Wz1b = wsw + OFF_Wz1b;
  const u16* Wz2b = wsw + OFF_Wz2b;
  const u16* Wz3b = wsw + OFF_Wz3b;
  const u16* Wz1t = wsw + OFF_Wz1t;
  const u16* Wz2t = wsw + OFF_Wz2t;
  const u16* Wz3t = wsw + OFF_Wz3t;
  const u16* Wz0t = wsw + OFF_Wz0t;
  const u16* Wx0t = wsw + OFF_Wx0t;
  const u16* Wx1t = wsw + OFF_Wx1t;
  const u16* Wx2t = wsw + OFF_Wx2t;
  u64* slab0 = (u64*)(wsw + OFF_S0);
  u64* slab1 = (u64*)(wsw + OFF_S1);
  u64* slab2 = (u64*)(wsw + OFF_S2);

  // LDS-only barrier: orders zbuf ds ops across waves; global stores and
  // weight DMAs stay in flight (per-wave vmcnt retires in-order, so fwdH's
  // counted waits remain correct).
  auto lbar = [&]() {
    asm volatile("s_waitcnt lgkmcnt(0)" ::: "memory");
    __builtin_amdgcn_s_barrier();
    asm volatile("" ::: "memory");
  };

  // ---- stage x = state-1 into xbuf (bf16, padded row-major) ----
  {
    int r = tid >> 4, c0 = (tid & 15) << 2;  // 64 rows x 16 chunks of 4 floats
    const float* p = state + (blk * BM + r) * D + c0;
    f32x4 v = __builtin_nontemporal_load((const f32x4*)p);
    u32* dst = (u32*)&xbuf[r * 72 + c0];
    dst[0] = f2b(v[0] - 1.0f) | (f2b(v[1] - 1.0f) << 16);
    dst[1] = f2b(v[2] - 1.0f) | (f2b(v[3] - 1.0f) << 16);
  }

  f32x4 acc[4][2];                  // 32 acc regs: 64 rows x 32 cols / wave
  const f32x4 Z = {0.f, 0.f, 0.f, 0.f};
  f32x4 pk = Z;                     // grad park: wave's single 16x16 out tile

  // K-major zbuf reads: A-frag (row tile mt, K-step st): lane(q,l15) needs
  // z[mt*16+l15][st*32+q*8..+8] -> offset (st*4+mt)*512 + q*128 + l15*8.
  // 64 lanes cover one contiguous 1KB span: zero bank conflicts.
  auto ldA = [&](int mt, int step) -> bf16x8 {
    return *(const bf16x8*)(&zbuf[(step * 4 + mt) * 512 + q * 128 + l15 * 8]);
  };
  auto ldX = [&](int mt, int ks) -> bf16x8 {       // x A-frag from padded xbuf
    return *(const bf16x8*)(&xbuf[(mt * 16 + l15) * 72 + ks * 32 + q * 8]);
  };
  auto wrZ = [&](int row, int n, u16 bits) {       // K-major scatter write
    zbuf[((n >> 5) * 4 + (row >> 4)) * 512 + ((n >> 3) & 3) * 128 +
         (row & 15) * 8 + (n & 7)] = bits;
  };

  // DMA one K-step slice into wbuf[buf]: wave stages its OWN 2 col-tiles
  // (w*2, w*2+1), 1 KB each; 16 waves cover the 32-tile slice. PRIVATE:
  // this wave reads exactly these two slots, so its vmcnt guards them.
  auto stageW = [&](const u16* Wp, int st, int buf) {
    const u16* gb = Wp + ((w * 2) * 16 + st) * 512 + lane * 8;
    u16* lb = &wbuf[buf * 16384 + (w * 2) * 512];
#pragma unroll
    for (int j = 0; j < 2; ++j)
      __builtin_amdgcn_global_load_lds(
          (const __attribute__((address_space(1))) void*)(gb + j * 16 * 512),
          (__attribute__((address_space(3))) void*)(lb + j * 512), 16, 0, 0);
  };

  // acc (+)= x @ Wx^T (K=64). zero_first: overwrite acc on ks==0.
  auto fwdX = [&](const u16* Wxp, bool zero_first) {
    const u16* xb = Wxp + lane * 8;
#pragma unroll
    for (int ks = 0; ks < 2; ++ks) {
      bf16x8 b2[2];
#pragma unroll
      for (int nt = 0; nt < 2; ++nt)
        b2[nt] = *(const bf16x8*)(xb + ((w * 2 + nt) * 2 + ks) * 512);
#pragma unroll
      for (int mt = 0; mt < 4; ++mt) {
        bf16x8 ax = ldX(mt, ks);
#pragma unroll
        for (int nt = 0; nt < 2; ++nt) {
          f32x4 c = (zero_first && ks == 0) ? Z : acc[mt][nt];
          acc[mt][nt] = __builtin_amdgcn_mfma_f32_16x16x32_bf16(ax, b2[nt], c, 0, 0, 0);
        }
      }
    }
  };

  // acc = zbuf @ W^T (K=512), zero-start. Contract: step 0 already staged
  // into wbuf[0] by the caller. Per-wave vmcnt(2): wait only the previous
  // step's 2 DMAs (everything older retires in-order first).
  auto fwdH = [&](const u16* Wp) {
#pragma unroll
    for (int st = 0; st < 16; ++st) {
      if (st < 15) {
        stageW(Wp, st + 1, (st + 1) & 1);
        asm volatile("s_waitcnt vmcnt(2)" ::: "memory");
      } else {
        asm volatile("s_waitcnt vmcnt(0)" ::: "memory");
      }
      const u16* wb = &wbuf[(st & 1) * 16384 + (w * 2) * 512 + lane * 8];
      bf16x8 a[4];
#pragma unroll
      for (int mt = 0; mt < 4; ++mt) a[mt] = ldA(mt, st);
#pragma unroll
      for (int nt = 0; nt < 2; ++nt) {
        bf16x8 b = *(const bf16x8*)(wb + nt * 512);
#pragma unroll
        for (int mt = 0; mt < 4; ++mt)
          acc[mt][nt] = __builtin_amdgcn_mfma_f32_16x16x32_bf16(
              a[mt], b, (st == 0) ? Z : acc[mt][nt], 0, 0, 0);
      }
    }
  };

  // forward epilogue: a+=bias; z=softplus -> zbuf; s=sigmoid -> slab
  auto fwd_epi = [&](const float* biasp, u64* slab) {
    float bias[2];
#pragma unroll
    for (int nt = 0; nt < 2; ++nt) bias[nt] = biasp[(w * 2 + nt) * 16 + l15];
#pragma unroll
    for (int mt = 0; mt < 4; ++mt)
#pragma unroll
      for (int nt = 0; nt < 2; ++nt) {
        int n = (w * 2 + nt) * 16 + l15;
        f32x4 A = acc[mt][nt];
        u64 pack = 0;
#pragma unroll
        for (int r = 0; r < 4; ++r) {
          float a = A[r] + bias[nt];
          float t = __expf(-a);
          float u = 1.0f + t;
          float s = __builtin_amdgcn_rcpf(u);     // sigmoid(a)
          float z = a + __logf(u);                // softplus(a)
          pack |= (u64)f2b(s) << (16 * r);
          wrZ(mt * 16 + q * 4 + r, n, (u16)f2b(z));
        }
        slab[((blk * 16 + w) * 8 + mt * 2 + nt) * 64 + lane] = pack;
      }
  };
  auto d3_epi = [&](const float* biasp) {   // d3 = WzL * sigmoid(a3) -> zbuf
    float bias[2], wl[2];
#pragma unroll
    for (int nt = 0; nt < 2; ++nt) {
      bias[nt] = biasp[(w * 2 + nt) * 16 + l15];
      wl[nt] = WzL[(w * 2 + nt) * 16 + l15];
    }
#pragma unroll
    for (int mt = 0; mt < 4; ++mt)
#pragma unroll
      for (int nt = 0; nt < 2; ++nt) {
        int n = (w * 2 + nt) * 16 + l15;
        f32x4 A = acc[mt][nt];
#pragma unroll
        for (int r = 0; r < 4; ++r) {
          float a = A[r] + bias[nt];
          float t = __expf(-a);
          float s = __builtin_amdgcn_rcpf(1.0f + t);
          wrZ(mt * 16 + q * 4 + r, n, (u16)f2b(wl[nt] * s));
        }
      }
  };
  // d = g * s -> zbuf (slab read once, same thread that wrote it)
  auto bwd_epi = [&](const u64* slab) {
    u64 v[4][2];
#pragma unroll
    for (int mt = 0; mt < 4; ++mt)
#pragma unroll
      for (int nt = 0; nt < 2; ++nt)
        v[mt][nt] = slab[((blk * 16 + w) * 8 + mt * 2 + nt) * 64 + lane];
#pragma unroll
    for (int mt = 0; mt < 4; ++mt)
#pragma unroll
      for (int nt = 0; nt < 2; ++nt) {
        int n = (w * 2 + nt) * 16 + l15;
        f32x4 A = acc[mt][nt];
#pragma unroll
        for (int r = 0; r < 4; ++r) {
          float s = b2f((u32)(v[mt][nt] >> (16 * r)) & 0xffffu);
          wrZ(mt * 16 + q * 4 + r, n, (u16)f2b(A[r] * s));
        }
      }
  };

  // grad mini-phase: pk += zbuf(d) @ Wg (main acc is DEAD here).
  // 16 waves <-> 16 out tiles: wave w owns tile (rt=w&3, ct=w>>2).
  // unroll 4: caps hoisted g-loads at 4 frags (full unroll spilled in R5).
  auto minigrad = [&](const u16* Wg, bool init) {
    int rt = w & 3, ct = w >> 2;
    const u16* gb = Wg + lane * 8;
    f32x4 t = init ? Z : pk;
#pragma unroll 4
    for (int st = 0; st < 16; ++st) {
      bf16x8 a = ldA(rt, st);
      bf16x8 g = *(const bf16x8*)(gb + (ct * 16 + st) * 512);
      t = __builtin_amdgcn_mfma_f32_16x16x32_bf16(a, g, t, 0, 0, 0);
    }
    pk = t;
  };

  // ---------------- forward ----------------
  lbar();                                   // xbuf ready
  fwdX(Wz0b, true);                         // a0 = x@Wz0^T
  stageW(Wz1b, 0, 0);                       // prestage; overlaps epilogue
  fwd_epi(bz0, slab0);
  lbar();
  fwdH(Wz1b); fwdX(Wx0b, false);            // a1 = z0@Wz1^T + x@Wx0^T
  lbar();
  stageW(Wz2b, 0, 0);
  fwd_epi(bx0, slab1);
  lbar();
  fwdH(Wz2b); fwdX(Wx1b, false);
  lbar();
  stageW(Wz3b, 0, 0);
  fwd_epi(bx1, slab2);
  lbar();
  fwdH(Wz3b); fwdX(Wx2b, false);            // a3 (last use of xbuf)
  lbar();
  stageW(Wz3t, 0, 0);                       // prestage bwd chain
  d3_epi(bx2);                              // d3 -> zbuf
  lbar();
  // ---------------- backward ----------------
  minigrad(Wx2t, true);                     // pk  = d3@Wx2t
  fwdH(Wz3t);                               // acc = d3@Wz3
  lbar();
  stageW(Wz2t, 0, 0);
  bwd_epi(slab2);                           // d2 -> zbuf
  lbar();
  minigrad(Wx1t, false);                    // pk += d2@Wx1t
  fwdH(Wz2t);                               // acc = d2@Wz2
  lbar();
  stageW(Wz1t, 0, 0);
  bwd_epi(slab1);                           // d1 -> zbuf
  lbar();
  minigrad(Wx0t, false);                    // pk += d1@Wx0t
  fwdH(Wz1t);                               // acc = d1@Wz1
  lbar();
  bwd_epi(slab0);                           // d0 -> zbuf
  lbar();
  // ---- final: out = d0@Wz0t + pk + WxL ----
  minigrad(Wz0t, false);                    // pk += d0@Wz0t
  {
    int rt = w & 3, ct = w >> 2;
    float wx = WxL[ct * 16 + l15];
#pragma unroll
    for (int r = 0; r < 4; ++r) {
      int row = blk * BM + rt * 16 + q * 4 + r;
      out[row * D + ct * 16 + l15] = pk[r] + wx;
    }
  }
}

extern "C" void kernel_launch(void* const* d_in, const int* in_sizes, int n_in,
                              void* d_out, int out_size, void* d_ws, size_t ws_size,
                              hipStream_t stream) {
  const float* state = (const float*)d_in[0];
  const float* Wz0 = (const float*)d_in[1];
  const float* bz0 = (const float*)d_in[2];
  const float* Wz1 = (const float*)d_in[3];
  const float* Wz2 = (const float*)d_in[4];
  const float* Wz3 = (const float*)d_in[5];
  const float* WzL = (const float*)d_in[6];
  const float* Wx0 = (const float*)d_in[7];
  const float* bx0 = (const float*)d_in[8];
  const float* Wx1 = (const float*)d_in[9];
  const float* bx1 = (const float*)d_in[10];
  const float* Wx2 = (const float*)d_in[11];
  const float* bx2 = (const float*)d_in[12];
  const float* WxL = (const float*)d_in[13];

  if (ws_size < (size_t)WS_ELEMS * 2) {
    fill_sentinel<<<(out_size + 255) / 256, 256, 0, stream>>>((float*)d_out, out_size);
    return;
  }
  u16* wsw = (u16*)d_ws;
  prep_kernel<<<OFF_WEND / 256, 256, 0, stream>>>(Wz0, Wz1, Wz2, Wz3, Wx0, Wx1, Wx2, wsw);
  icnn_kernel<<<B_TOTAL / BM, 1024, 0, stream>>>(state, bz0, bx0, bx1, bx2, WzL, WxL,
                                                 wsw, (float*)d_out);
}

// Round 8
// 441.783 us; speedup vs baseline: 1.7788x; 1.1186x over previous
//
#include <hip/hip_runtime.h>

typedef unsigned short u16;
typedef unsigned int u32;
typedef unsigned long long u64;

#define B_TOTAL 65536
#define H 512
#define D 64
#define BM 64

typedef __bf16 bf16x8 __attribute__((ext_vector_type(8)));
typedef float f32x4 __attribute__((ext_vector_type(4)));

__device__ __forceinline__ u32 f2b(float f) {  // fp32 -> bf16 bits, RNE
  u32 u = __builtin_bit_cast(u32, f);
  return (u + 0x7fffu + ((u >> 16) & 1u)) >> 16;
}
__device__ __forceinline__ float b2f(u32 bits) {
  return __builtin_bit_cast(float, bits << 16);
}

// ---- workspace layout (bf16 element offsets) ----
// Weight regions are FRAGMENT-PACKED: for logical B-matrix M[NN][KK],
// packed[( (n>>4)*(KK/32) + (k>>5) )*512 + lane*8 + j] = M[n][k],
// n = ntile*16 + (lane&15), k = kstep*32 + (lane>>4)*8 + j.
#define OFF_Wz0b 0          /* [N=512][K=64]  fwd L0 */
#define OFF_Wx0b 32768
#define OFF_Wx1b 65536
#define OFF_Wx2b 98304
#define OFF_Wz1b 131072     /* [N=512][K=512] fwd */
#define OFF_Wz2b 393216
#define OFF_Wz3b 655360
#define OFF_Wz1t 917504     /* [N=512][K=512] transposed, bwd */
#define OFF_Wz2t 1179648
#define OFF_Wz3t 1441792
#define OFF_Wz0t 1703936    /* [N=64][K=512] transposed grad weights */
#define OFF_Wx0t 1736704
#define OFF_Wx1t 1769472
#define OFF_Wx2t 1802240
#define OFF_WEND 1835008
#define SLAB_ELEMS (B_TOTAL * H)          /* 33,554,432 bf16 per slab */
#define OFF_S0 OFF_WEND
#define OFF_S1 (OFF_S0 + SLAB_ELEMS)
#define OFF_S2 (OFF_S1 + SLAB_ELEMS)
#define WS_ELEMS (OFF_S2 + SLAB_ELEMS)    /* ~102.5M elems = ~205 MB */

// ---- weight prep: fp32 -> bf16, fragment-packed (+ transposed variants) ----
__global__ __launch_bounds__(256) void prep_kernel(
    const float* __restrict__ Wz0, const float* __restrict__ Wz1,
    const float* __restrict__ Wz2, const float* __restrict__ Wz3,
    const float* __restrict__ Wx0, const float* __restrict__ Wx1,
    const float* __restrict__ Wx2, u16* __restrict__ wsb) {
  int i = blockIdx.x * 256 + threadIdx.x;   // grid exactly covers OFF_WEND
  const float* src;
  int NN, KK, trans, p;
  if (i < 131072) {                          // x-path fwd: [512][64] direct
    int r = i >> 15; p = i & 32767;
    src = (r == 0) ? Wz0 : (r == 1) ? Wx0 : (r == 2) ? Wx1 : Wx2;
    NN = 512; KK = 64; trans = 0;
  } else if (i < 917504) {                   // H fwd: [512][512] direct
    int j = i - 131072; int r = j >> 18; p = j & 262143;
    src = (r == 0) ? Wz1 : (r == 1) ? Wz2 : Wz3;
    NN = 512; KK = 512; trans = 0;
  } else if (i < 1703936) {                  // H bwd: transposed
    int j = i - 917504; int r = j >> 18; p = j & 262143;
    src = (r == 0) ? Wz1 : (r == 1) ? Wz2 : Wz3;
    NN = 512; KK = 512; trans = 1;
  } else {                                   // grad weights: [64][512] = W^T
    int j = i - 1703936; int r = j >> 15; p = j & 32767;
    src = (r == 0) ? Wz0 : (r == 1) ? Wx0 : (r == 2) ? Wx1 : Wx2;
    NN = 64; KK = 512; trans = 1;
  }
  int jj = p & 7, lane = (p >> 3) & 63, blk = p >> 9;
  int kt_sh = (KK == 64) ? 1 : 4;            // log2(KK/32)
  int ntile = blk >> kt_sh;
  int kstep = blk & ((1 << kt_sh) - 1);
  int n = ntile * 16 + (lane & 15);
  int k = kstep * 32 + ((lane >> 4) << 3) + jj;
  float v = trans ? src[k * NN + n] : src[n * KK + k];
  wsb[i] = (u16)f2b(v);
}

__global__ __launch_bounds__(256) void fill_sentinel(float* out, int n) {
  int i = blockIdx.x * 256 + threadIdx.x;
  if (i < n) out[i] = 12345.0f;   // unmistakable "workspace too small" marker
}

// ---- fully-fused ICNN fwd+bwd (single GEMM kernel) ----
// ROUND-8 = ROUND-7 (478us, correct) + two coupled changes:
//  (1) B WEIGHTS STREAM GLOBAL->VGPR (depth-1 rotation bc/bn, unroll-1):
//      wbuf + global_load_lds + vmcnt discipline deleted. B is per-wave
//      private and L2-resident (all weights 3.7MB < 4MB/XCD L2), so this
//      moves ~1MB/fwdH (B-reads + DMA-writes) off the LDS banks (fwdH was
//      LDS-BW-bound: 2.0MB LDS vs 4.1us MFMA) onto the idle L2 path.
//      R4's streaming failed at 2 waves/SIMD with no rotation; here 4
//      waves/SIMD TLP + explicit prefetch. Live set ~88 regs < 128 cap.
//  (2) PING-PONG zbuf (the freed 64KB): epi writes zb[nxt] while the
//      current phase still owns zb[cur] -> the WAR barrier per layer
//      disappears. Barriers 21 -> 8; each phase is a merged
//      [minigrad | fwdX | fwdH | epi] region so resident waves skew
//      across MFMA/VALU/LDS instead of lockstep pipe-alternation.
// Ownership stays R7 col-split (wave w: cols [w*32,+32), acc[4][2]).
// K-major zbuf (conflict-free ldA) kept. LDS-only barriers kept.
// LDS = 2x64K zbuf + 9.2K xbuf = 137 KB, 1 block/CU, 16 waves.
__global__ __launch_bounds__(1024, 4) void icnn_kernel(
    const float* __restrict__ state,
    const float* __restrict__ bz0, const float* __restrict__ bx0,
    const float* __restrict__ bx1, const float* __restrict__ bx2,
    const float* __restrict__ WzL, const float* __restrict__ WxL,
    u16* __restrict__ wsw, float* __restrict__ out) {
  __shared__ u16 zbA[BM * H];       // K-major activations, ping  (64 KB)
  __shared__ u16 zbB[BM * H];       // K-major activations, pong  (64 KB)
  __shared__ u16 xbuf[BM * 72];     // padded x staging, 9.2 KB

  const int tid = threadIdx.x;
  const int w = tid >> 6;           // 0..15
  const int lane = tid & 63;
  const int l15 = lane & 15;
  const int q = lane >> 4;
  const int blk = blockIdx.x;

  const u16* Wz0b = wsw + OFF_Wz0b;
  const u16* Wx0b = wsw + OFF_Wx0b;
  const u16* Wx1b = wsw + OFF_Wx1b;
  const u16* Wx2b = wsw + OFF_Wx2b;
  const u16* Wz1b = wsw + OFF_Wz1b;
  const u16* Wz2b = wsw + OFF_Wz2b;
  const u16* Wz3b = wsw + OFF_Wz3b;
  const u16* Wz1t = wsw + OFF_Wz1t;
  const u16* Wz2t = wsw + OFF_Wz2t;
  const u16* Wz3t = wsw + OFF_Wz3t;
  const u16* Wz0t = wsw + OFF_Wz0t;
  const u16* Wx0t = wsw + OFF_Wx0t;
  const u16* Wx1t = wsw + OFF_Wx1t;
  const u16* Wx2t = wsw + OFF_Wx2t;
  u64* slab0 = (u64*)(wsw + OFF_S0);
  u64* slab1 = (u64*)(wsw + OFF_S1);
  u64* slab2 = (u64*)(wsw + OFF_S2);

  // LDS-only barrier: orders zbuf ds ops across waves; global loads/stores
  // stay in flight across it (no vmcnt drain).
  auto lbar = [&]() {
    asm volatile("s_waitcnt lgkmcnt(0)" ::: "memory");
    __builtin_amdgcn_s_barrier();
    asm volatile("" ::: "memory");
  };

  // ---- stage x = state-1 into xbuf (bf16, padded row-major) ----
  {
    int r = tid >> 4, c0 = (tid & 15) << 2;  // 64 rows x 16 chunks of 4 floats
    const float* p = state + (blk * BM + r) * D + c0;
    f32x4 v = __builtin_nontemporal_load((const f32x4*)p);
    u32* dst = (u32*)&xbuf[r * 72 + c0];
    dst[0] = f2b(v[0] - 1.0f) | (f2b(v[1] - 1.0f) << 16);
    dst[1] = f2b(v[2] - 1.0f) | (f2b(v[3] - 1.0f) << 16);
  }

  f32x4 acc[4][2];                  // 32 acc regs: 64 rows x 32 cols / wave
  const f32x4 Z = {0.f, 0.f, 0.f, 0.f};
  f32x4 pk = Z;                     // grad park: wave's single 16x16 out tile

  // K-major zbuf reads: A-frag (row tile mt, K-step st): lane(q,l15) needs
  // z[mt*16+l15][st*32+q*8..+8] -> offset (st*4+mt)*512 + q*128 + l15*8.
  // 64 lanes cover one contiguous 1KB span: zero bank conflicts.
  auto ldA = [&](const u16* zb, int mt, int step) -> bf16x8 {
    return *(const bf16x8*)(&zb[(step * 4 + mt) * 512 + q * 128 + l15 * 8]);
  };
  auto ldX = [&](int mt, int ks) -> bf16x8 {       // x A-frag from padded xbuf
    return *(const bf16x8*)(&xbuf[(mt * 16 + l15) * 72 + ks * 32 + q * 8]);
  };
  auto wrZ = [&](u16* zb, int row, int n, u16 bits) {  // K-major scatter write
    zb[((n >> 5) * 4 + (row >> 4)) * 512 + ((n >> 3) & 3) * 128 +
       (row & 15) * 8 + (n & 7)] = bits;
  };

  // acc = x @ Wx^T (K=64), zero-start. Wx streams global->VGPR.
  auto fwdX = [&](const u16* Wxp) {
    const u16* xb = Wxp + lane * 8;
#pragma unroll
    for (int ks = 0; ks < 2; ++ks) {
      bf16x8 b2[2];
#pragma unroll
      for (int nt = 0; nt < 2; ++nt)
        b2[nt] = *(const bf16x8*)(xb + ((w * 2 + nt) * 2 + ks) * 512);
#pragma unroll
      for (int mt = 0; mt < 4; ++mt) {
        bf16x8 ax = ldX(mt, ks);
#pragma unroll
        for (int nt = 0; nt < 2; ++nt) {
          f32x4 c = (ks == 0) ? Z : acc[mt][nt];
          acc[mt][nt] = __builtin_amdgcn_mfma_f32_16x16x32_bf16(ax, b2[nt], c, 0, 0, 0);
        }
      }
    }
  };

  // acc (+)= zb @ W^T (K=512). B streams global->VGPR with depth-1
  // rotation: bn (next step) issues before this step's MFMAs, so the
  // compiler's vmcnt wait on bc lands a full iteration after issue.
  auto fwdH = [&](const u16* Wp, const u16* zb, bool zero) {
    const u16* gb = Wp + (w * 2 * 16) * 512 + lane * 8;
    bf16x8 bc0 = *(const bf16x8*)(gb);
    bf16x8 bc1 = *(const bf16x8*)(gb + 16 * 512);
#pragma unroll 1
    for (int st = 0; st < 16; ++st) {
      int stn = (st < 15) ? st + 1 : st;     // clamp: harmless re-read at tail
      bf16x8 bn0 = *(const bf16x8*)(gb + stn * 512);
      bf16x8 bn1 = *(const bf16x8*)(gb + (16 + stn) * 512);
      bf16x8 a[4];
#pragma unroll
      for (int mt = 0; mt < 4; ++mt) a[mt] = ldA(zb, mt, st);
#pragma unroll
      for (int mt = 0; mt < 4; ++mt)
        acc[mt][0] = __builtin_amdgcn_mfma_f32_16x16x32_bf16(
            a[mt], bc0, (zero && st == 0) ? Z : acc[mt][0], 0, 0, 0);
#pragma unroll
      for (int mt = 0; mt < 4; ++mt)
        acc[mt][1] = __builtin_amdgcn_mfma_f32_16x16x32_bf16(
            a[mt], bc1, (zero && st == 0) ? Z : acc[mt][1], 0, 0, 0);
      bc0 = bn0; bc1 = bn1;
    }
  };

  // forward epilogue: a+=bias; z=softplus -> zb; s=sigmoid -> slab
  auto fwd_epi = [&](const float* biasp, u64* slab, u16* zb) {
    float bias[2];
#pragma unroll
    for (int nt = 0; nt < 2; ++nt) bias[nt] = biasp[(w * 2 + nt) * 16 + l15];
#pragma unroll
    for (int mt = 0; mt < 4; ++mt)
#pragma unroll
      for (int nt = 0; nt < 2; ++nt) {
        int n = (w * 2 + nt) * 16 + l15;
        f32x4 A = acc[mt][nt];
        u64 pack = 0;
#pragma unroll
        for (int r = 0; r < 4; ++r) {
          float a = A[r] + bias[nt];
          float t = __expf(-a);
          float u = 1.0f + t;
          float s = __builtin_amdgcn_rcpf(u);     // sigmoid(a)
          float z = a + __logf(u);                // softplus(a)
          pack |= (u64)f2b(s) << (16 * r);
          wrZ(zb, mt * 16 + q * 4 + r, n, (u16)f2b(z));
        }
        slab[((blk * 16 + w) * 8 + mt * 2 + nt) * 64 + lane] = pack;
      }
  };
  auto d3_epi = [&](const float* biasp, u16* zb) {  // d3 = WzL*sigmoid(a3)
    float bias[2], wl[2];
#pragma unroll
    for (int nt = 0; nt < 2; ++nt) {
      bias[nt] = biasp[(w * 2 + nt) * 16 + l15];
      wl[nt] = WzL[(w * 2 + nt) * 16 + l15];
    }
#pragma unroll
    for (int mt = 0; mt < 4; ++mt)
#pragma unroll
      for (int nt = 0; nt < 2; ++nt) {
        int n = (w * 2 + nt) * 16 + l15;
        f32x4 A = acc[mt][nt];
#pragma unroll
        for (int r = 0; r < 4; ++r) {
          float a = A[r] + bias[nt];
          float t = __expf(-a);
          float s = __builtin_amdgcn_rcpf(1.0f + t);
          wrZ(zb, mt * 16 + q * 4 + r, n, (u16)f2b(wl[nt] * s));
        }
      }
  };
  // d = g * s -> zb (slab read once, same thread that wrote it)
  auto bwd_epi = [&](const u64* slab, u16* zb) {
    u64 v[4][2];
#pragma unroll
    for (int mt = 0; mt < 4; ++mt)
#pragma unroll
      for (int nt = 0; nt < 2; ++nt)
        v[mt][nt] = slab[((blk * 16 + w) * 8 + mt * 2 + nt) * 64 + lane];
#pragma unroll
    for (int mt = 0; mt < 4; ++mt)
#pragma unroll
      for (int nt = 0; nt < 2; ++nt) {
        int n = (w * 2 + nt) * 16 + l15;
        f32x4 A = acc[mt][nt];
#pragma unroll
        for (int r = 0; r < 4; ++r) {
          float s = b2f((u32)(v[mt][nt] >> (16 * r)) & 0xffffu);
          wrZ(zb, mt * 16 + q * 4 + r, n, (u16)f2b(A[r] * s));
        }
      }
  };

  // grad mini-phase: pk += zb(d) @ Wg (main acc is DEAD here).
  // 16 waves <-> 16 out tiles: wave w owns tile (rt=w&3, ct=w>>2).
  // unroll 4: caps hoisted g-loads at 4 frags (full unroll spilled in R5).
  auto minigrad = [&](const u16* Wg, const u16* zb, bool init) {
    int rt = w & 3, ct = w >> 2;
    const u16* gb = Wg + lane * 8;
    f32x4 t = init ? Z : pk;
#pragma unroll 4
    for (int st = 0; st < 16; ++st) {
      bf16x8 a = ldA(zb, rt, st);
      bf16x8 g = *(const bf16x8*)(gb + (ct * 16 + st) * 512);
      t = __builtin_amdgcn_mfma_f32_16x16x32_bf16(a, g, t, 0, 0, 0);
    }
    pk = t;
  };

  // ---------------- forward ----------------
  lbar();                                   // xbuf ready
  fwdX(Wz0b);                               // a0 = x@Wz0^T
  fwd_epi(bz0, slab0, zbA);                 // z0 -> zbA
  lbar();                                   // P0 done
  fwdX(Wx0b); fwdH(Wz1b, zbA, false);       // a1 = x@Wx0^T + z0@Wz1^T
  fwd_epi(bx0, slab1, zbB);                 // z1 -> zbB (zbA still readable)
  lbar();                                   // P1
  fwdX(Wx1b); fwdH(Wz2b, zbB, false);       // a2
  fwd_epi(bx1, slab2, zbA);                 // z2 -> zbA
  lbar();                                   // P2
  fwdX(Wx2b); fwdH(Wz3b, zbA, false);       // a3
  d3_epi(bx2, zbB);                         // d3 -> zbB
  lbar();                                   // P3
  // ---------------- backward ----------------
  minigrad(Wx2t, zbB, true);                // pk  = d3@Wx2t
  fwdH(Wz3t, zbB, true);                    // acc = d3@Wz3
  bwd_epi(slab2, zbA);                      // d2 -> zbA
  lbar();                                   // P4
  minigrad(Wx1t, zbA, false);               // pk += d2@Wx1t
  fwdH(Wz2t, zbA, true);                    // acc = d2@Wz2
  bwd_epi(slab1, zbB);                      // d1 -> zbB
  lbar();                                   // P5
  minigrad(Wx0t, zbB, false);               // pk += d1@Wx0t
  fwdH(Wz1t, zbB, true);                    // acc = d1@Wz1
  bwd_epi(slab0, zbA);                      // d0 -> zbA
  lbar();                                   // P6
  // ---- final: out = d0@Wz0t + pk + WxL ----
  minigrad(Wz0t, zbA, false);               // pk += d0@Wz0t
  {
    int rt = w & 3, ct = w >> 2;
    float wx = WxL[ct * 16 + l15];
#pragma unroll
    for (int r = 0; r < 4; ++r) {
      int row = blk * BM + rt * 16 + q * 4 + r;
      out[row * D + ct * 16 + l15] = pk[r] + wx;
    }
  }
}

extern "C" void kernel_launch(void* const* d_in, const int* in_sizes, int n_in,
                              void* d_out, int out_size, void* d_ws, size_t ws_size,
                              hipStream_t stream) {
  const float* state = (const float*)d_in[0];
  const float* Wz0 = (const float*)d_in[1];
  const float* bz0 = (const float*)d_in[2];
  const float* Wz1 = (const float*)d_in[3];
  const float* Wz2 = (const float*)d_in[4];
  const float* Wz3 = (const float*)d_in[5];
  const float* WzL = (const float*)d_in[6];
  const float* Wx0 = (const float*)d_in[7];
  const float* bx0 = (const float*)d_in[8];
  const float* Wx1 = (const float*)d_in[9];
  const float* bx1 = (const float*)d_in[10];
  const float* Wx2 = (const float*)d_in[11];
  const float* bx2 = (const float*)d_in[12];
  const float* WxL = (const float*)d_in[13];

  if (ws_size < (size_t)WS_ELEMS * 2) {
    fill_sentinel<<<(out_size + 255) / 256, 256, 0, stream>>>((float*)d_out, out_size);
    return;
  }
  u16* wsw = (u16*)d_ws;
  prep_kernel<<<OFF_WEND / 256, 256, 0, stream>>>(Wz0, Wz1, Wz2, Wz3, Wx0, Wx1, Wx2, wsw);
  icnn_kernel<<<B_TOTAL / BM, 1024, 0, stream>>>(state, bz0, bx0, bx1, bx2, WzL, WxL,
                                                 wsw, (float*)d_out);
}